// Round 14
// baseline (499.017 us; speedup 1.0000x reference)
//
#include <hip/hip_runtime.h>
#include <hip/hip_bf16.h>
#include <stdint.h>

#define B_   8
#define S_   1024
#define D_   256
#define H_   8
#define DH_  32
#define L_   4
#define V_   100
#define DFF_ 1024
#define M_   (B_*S_)   // 8192

using bf16 = __hip_bfloat16;
typedef __bf16 bf16x8 __attribute__((ext_vector_type(8)));
typedef float  f32x4  __attribute__((ext_vector_type(4)));

static __device__ __forceinline__ float b2f(unsigned short u) {
  union { unsigned int i; float f; } w; w.i = ((unsigned int)u) << 16; return w.f;
}
static __device__ __forceinline__ unsigned short f2b(float f) {
  bf16 h = (bf16)f; return *(unsigned short*)&h;
}

// async global->LDS DMA: 16B/lane, LDS dest = wave-uniform base + lane*16
static __device__ __forceinline__ void load_lds16(const void* g, void* l) {
  __builtin_amdgcn_global_load_lds((const __attribute__((address_space(1))) void*)g,
                                   (__attribute__((address_space(3))) void*)l,
                                   16, 0, 0);
}

// LDS bank swizzle (see r9): global-source chunk permutation, 2-way aliasing.
#define SRC_CHS(tid)  ((((tid) & 3) ^ (((tid) >> 3) & 3)) * 8)
#define FRAG_Q8(quad, l15)  (((quad) ^ (((l15) >> 1) & 3)) * 8)

// DPP cross-lane reductions over the 16-lane l15 group (== DPP row).
template<int CTRL>
static __device__ __forceinline__ float dppf(float v) {
  union { float f; int i; } a, r;
  a.f = v;
  r.i = __builtin_amdgcn_update_dpp(0, a.i, CTRL, 0xF, 0xF, true);
  return r.f;
}
static __device__ __forceinline__ float red_sum16(float v) {
  v += dppf<0xB1>(v);
  v += dppf<0x4E>(v);
  v += dppf<0x141>(v);
  v += dppf<0x140>(v);
  return v;
}

// ---------------------------------------------------------------------------
// Tiled weight prep: f32 [R][C] -> bf16 [C][R], 32x32 LDS tiles, coalesced.
// ---------------------------------------------------------------------------
__global__ void prep_t(const float* __restrict__ Wq, const float* __restrict__ Wk,
                       const float* __restrict__ Wv, const float* __restrict__ Wo,
                       const float* __restrict__ W1, const float* __restrict__ W2,
                       const float* __restrict__ Wc,
                       const float* __restrict__ bq, const float* __restrict__ bk,
                       const float* __restrict__ bv,
                       bf16* __restrict__ WqkvT, bf16* __restrict__ WoT,
                       bf16* __restrict__ W1T, bf16* __restrict__ W2T,
                       bf16* __restrict__ WcT, float* __restrict__ bqkv)
{
  const int z = blockIdx.z;
  if (z == 25) {
    if (blockIdx.x || blockIdx.y) return;
    const int tid = threadIdx.y*32 + threadIdx.x;
    for (int i = tid; i < L_*768; i += 256) {
      const int l2 = i / 768, j = i % 768;
      const float* src = (j < 256) ? bq : (j < 512) ? bk : bv;
      bqkv[i] = src[l2*256 + (j & 255)];
    }
    return;
  }
  const float* src; bf16* dst; int R, C, Cd;
  if (z < 12) {
    const int l = z / 3, w = z % 3;
    src = ((w == 0) ? Wq : (w == 1) ? Wk : Wv) + (size_t)l*65536;
    R = 256; C = 256; Cd = 256;
    dst = WqkvT + (size_t)l*196608 + (size_t)w*65536;
  } else if (z < 16) {
    const int l = z - 12;
    src = Wo + (size_t)l*65536; R = 256; C = 256; Cd = 256;
    dst = WoT + (size_t)l*65536;
  } else if (z < 20) {
    const int l = z - 16;
    src = W1 + (size_t)l*262144; R = 256; C = 1024; Cd = 1024;
    dst = W1T + (size_t)l*262144;
  } else if (z < 24) {
    const int l = z - 20;
    src = W2 + (size_t)l*262144; R = 1024; C = 256; Cd = 256;
    dst = W2T + (size_t)l*262144;
  } else {
    src = Wc; R = 256; C = 100; Cd = 128;
    dst = WcT;
  }
  const int c0 = blockIdx.x*32, r0 = blockIdx.y*32;
  if (c0 >= Cd || r0 >= R) return;
  __shared__ float t[32][33];
  #pragma unroll
  for (int i = 0; i < 4; ++i) {
    const int r = r0 + threadIdx.y + i*8;
    const int c = c0 + threadIdx.x;
    t[threadIdx.y + i*8][threadIdx.x] = (r < R && c < C) ? src[(size_t)r*C + c] : 0.f;
  }
  __syncthreads();
  #pragma unroll
  for (int i = 0; i < 4; ++i) {
    const int c = c0 + threadIdx.y + i*8;
    const int r = r0 + threadIdx.x;
    if (c < Cd && r < R)
      dst[(size_t)c*R + r] = (bf16)t[threadIdx.x][threadIdx.y + i*8];
  }
}

// ---------------------------------------------------------------------------
__global__ void embed_kernel(const int* __restrict__ ids, const float* __restrict__ emb,
                             bf16* __restrict__ x)
{
  const int bs = blockIdx.x;
  const int d  = threadIdx.x;
  const int s  = bs & (S_-1);
  const int id = ids[bs];
  const int f  = (d < 128) ? (2*d) : (2*(d-128)+1);
  const float inv = powf(10000.f, -(float)f * (1.f/256.f));
  const float pe  = sinf((float)s * inv);
  x[(size_t)bs*D_ + d] = (bf16)(emb[(size_t)id*D_ + d] + pe);
}

// ---------------------------------------------------------------------------
// QKV GEMM with packed epilogue -> qp[bh][s][32] (PRE-SCALED by
// log2(e)/sqrt(dh) for the exp2-based softmax), kp, vt[bh][d][s].
// ---------------------------------------------------------------------------
__global__ __launch_bounds__(256) void gemm_qkv(
    const bf16* __restrict__ A, const bf16* __restrict__ BT,
    const float* __restrict__ bias,
    bf16* __restrict__ qp, bf16* __restrict__ kp, bf16* __restrict__ vt)
{
  __shared__ bf16 As[128*32];
  __shared__ bf16 Bs[64*32];
  __shared__ bf16 Vs[64][136];
  const int tid  = threadIdx.x;
  const int lane = tid & 63, wave = tid >> 6;
  const int quad = lane >> 4, l15 = lane & 15;
  const int m0 = blockIdx.x * 128;
  const int n0 = blockIdx.y * 64;
  const int wm = (wave & 1) * 64;
  const int wn = (wave >> 1) * 32;
  const int K = 256;

  const bf16* a0 = A  + (size_t)m0 * K;
  const bf16* b0 = BT + (size_t)n0 * K;
  const int row = tid >> 2;
  const int chs = SRC_CHS(tid);
  const int q8  = FRAG_Q8(quad, l15);

  f32x4 acc[4][2] = {};

  for (int k0 = 0; k0 < K; k0 += 32) {
    __syncthreads();
    load_lds16(a0 + (size_t)row*K      + k0 + chs, (char*)As + (size_t)wave*1024);
    load_lds16(a0 + (size_t)(row+64)*K + k0 + chs, (char*)As + 4096 + (size_t)wave*1024);
    load_lds16(b0 + (size_t)row*K      + k0 + chs, (char*)Bs + (size_t)wave*1024);
    __syncthreads();
    bf16x8 af[4], bfr[2];
    #pragma unroll
    for (int mt = 0; mt < 4; ++mt)
      af[mt] = *(const bf16x8*)(As + (wm + mt*16 + l15)*32 + q8);
    #pragma unroll
    for (int nt = 0; nt < 2; ++nt)
      bfr[nt] = *(const bf16x8*)(Bs + (wn + nt*16 + l15)*32 + q8);
    #pragma unroll
    for (int mt = 0; mt < 4; ++mt)
      #pragma unroll
      for (int nt = 0; nt < 2; ++nt)
        acc[mt][nt] = __builtin_amdgcn_mfma_f32_16x16x32_bf16(af[mt], bfr[nt], acc[mt][nt], 0, 0, 0);
  }

  const int seg = n0 >> 8;            // 0=Q, 1=K, 2=V
  const int b  = m0 >> 10;
  const int s0 = m0 & 1023;

  if (seg < 2) {
    bf16* dst = seg ? kp : qp;
    // Q pre-scale: 1/sqrt(32) * log2(e)  (softmax uses exp2)
    const float sc = seg ? 1.f : (0.17677669529663687f * 1.4426950408889634f);
    #pragma unroll
    for (int nt = 0; nt < 2; ++nt) {
      const int n  = n0 + wn + nt*16 + l15;
      const int nn = n & 255;
      const int h = nn >> 5, d = nn & 31;
      const float bvs = bias[n];
      bf16* hb = dst + (((size_t)b*H_ + h)*S_)*DH_ + d;
      #pragma unroll
      for (int mt = 0; mt < 4; ++mt) {
        const int ml = wm + mt*16 + quad*4;
        #pragma unroll
        for (int r = 0; r < 4; ++r)
          hb[(size_t)(s0 + ml + r)*DH_] = (bf16)((acc[mt][nt][r] + bvs) * sc);
      }
    }
  } else {
    #pragma unroll
    for (int nt = 0; nt < 2; ++nt) {
      const int nl = wn + nt*16 + l15;
      const float bvs = bias[n0 + nl];
      #pragma unroll
      for (int mt = 0; mt < 4; ++mt) {
        const int ml = wm + mt*16 + quad*4;
        #pragma unroll
        for (int r = 0; r < 4; ++r)
          Vs[nl][ml + r] = (bf16)(acc[mt][nt][r] + bvs);
      }
    }
    __syncthreads();
    #pragma unroll
    for (int t = 0; t < 2; ++t) {
      const int vrow = (tid >> 3) + 32*t;
      const int soff = (tid & 7) * 16;
      const int nn = (n0 + vrow) & 255;
      const int h = nn >> 5, d = nn & 31;
      bf16* dst = vt + (((size_t)b*H_ + h)*DH_ + d)*S_ + s0 + soff;
      *(bf16x8*)dst       = *(const bf16x8*)&Vs[vrow][soff];
      *(bf16x8*)(dst + 8) = *(const bf16x8*)&Vs[vrow][soff + 8];
    }
  }
}

// ---------------------------------------------------------------------------
// Generic GEMM 128x64 tile (bias + optional relu) — used for FF1.
// ---------------------------------------------------------------------------
template<bool RELU, bool OUT_BF16>
__global__ __launch_bounds__(256) void gemm_bt(
    const bf16* __restrict__ A, const bf16* __restrict__ BT,
    const float* __restrict__ bias, void* __restrict__ C,
    int M, int N, int K)
{
  __shared__ bf16 As[128*32];
  __shared__ bf16 Bs[64*32];
  const int tid  = threadIdx.x;
  const int lane = tid & 63, wave = tid >> 6;
  const int quad = lane >> 4, l15 = lane & 15;
  const int m0 = blockIdx.x * 128;
  const int n0 = blockIdx.y * 64;
  const int wm = (wave & 1) * 64;
  const int wn = (wave >> 1) * 32;

  const bf16* a0 = A  + (size_t)m0 * K;
  const bf16* b0 = BT + (size_t)n0 * K;
  const int row = tid >> 2;
  const int chs = SRC_CHS(tid);
  const int q8  = FRAG_Q8(quad, l15);

  f32x4 acc[4][2] = {};

  for (int k0 = 0; k0 < K; k0 += 32) {
    __syncthreads();
    load_lds16(a0 + (size_t)row*K      + k0 + chs, (char*)As + (size_t)wave*1024);
    load_lds16(a0 + (size_t)(row+64)*K + k0 + chs, (char*)As + 4096 + (size_t)wave*1024);
    load_lds16(b0 + (size_t)row*K      + k0 + chs, (char*)Bs + (size_t)wave*1024);
    __syncthreads();
    bf16x8 af[4], bfr[2];
    #pragma unroll
    for (int mt = 0; mt < 4; ++mt)
      af[mt] = *(const bf16x8*)(As + (wm + mt*16 + l15)*32 + q8);
    #pragma unroll
    for (int nt = 0; nt < 2; ++nt)
      bfr[nt] = *(const bf16x8*)(Bs + (wn + nt*16 + l15)*32 + q8);
    #pragma unroll
    for (int mt = 0; mt < 4; ++mt)
      #pragma unroll
      for (int nt = 0; nt < 2; ++nt)
        acc[mt][nt] = __builtin_amdgcn_mfma_f32_16x16x32_bf16(af[mt], bfr[nt], acc[mt][nt], 0, 0, 0);
  }

  #pragma unroll
  for (int nt = 0; nt < 2; ++nt) {
    const int n = n0 + wn + nt*16 + l15;
    const float bvs = bias[n];
    #pragma unroll
    for (int mt = 0; mt < 4; ++mt) {
      const int mr = m0 + wm + mt*16 + quad*4;
      #pragma unroll
      for (int r = 0; r < 4; ++r) {
        float v = acc[mt][nt][r] + bvs;
        if (RELU) v = fmaxf(v, 0.f);
        if (OUT_BF16) ((bf16*)C)[(size_t)(mr + r)*N + n] = (bf16)v;
        else          ((float*)C)[(size_t)(mr + r)*N + n] = v;
      }
    }
  }
}

// ---------------------------------------------------------------------------
// GEMM 64x64 tile — classifier (NMASK).
// ---------------------------------------------------------------------------
template<bool RELU, bool OUT_BF16, bool NMASK>
__global__ __launch_bounds__(256) void gemm_bt64(
    const bf16* __restrict__ A, const bf16* __restrict__ BT,
    const float* __restrict__ bias, void* __restrict__ C,
    int M, int N, int K)
{
  __shared__ bf16 As[64*32];
  __shared__ bf16 Bs[64*32];
  const int tid  = threadIdx.x;
  const int lane = tid & 63, wave = tid >> 6;
  const int quad = lane >> 4, l15 = lane & 15;
  const int m0 = blockIdx.x * 64;
  const int n0 = blockIdx.y * 64;
  const int wm = (wave & 1) * 32;
  const int wn = (wave >> 1) * 32;

  const bf16* a0 = A  + (size_t)m0 * K;
  const bf16* b0 = BT + (size_t)n0 * K;
  const int row = tid >> 2;
  const int chs = SRC_CHS(tid);
  const int q8  = FRAG_Q8(quad, l15);

  f32x4 acc[2][2] = {};

  for (int k0 = 0; k0 < K; k0 += 32) {
    __syncthreads();
    load_lds16(a0 + (size_t)row*K + k0 + chs, (char*)As + (size_t)wave*1024);
    load_lds16(b0 + (size_t)row*K + k0 + chs, (char*)Bs + (size_t)wave*1024);
    __syncthreads();
    bf16x8 af[2], bfr[2];
    #pragma unroll
    for (int mt = 0; mt < 2; ++mt)
      af[mt] = *(const bf16x8*)(As + (wm + mt*16 + l15)*32 + q8);
    #pragma unroll
    for (int nt = 0; nt < 2; ++nt)
      bfr[nt] = *(const bf16x8*)(Bs + (wn + nt*16 + l15)*32 + q8);
    #pragma unroll
    for (int mt = 0; mt < 2; ++mt)
      #pragma unroll
      for (int nt = 0; nt < 2; ++nt)
        acc[mt][nt] = __builtin_amdgcn_mfma_f32_16x16x32_bf16(af[mt], bfr[nt], acc[mt][nt], 0, 0, 0);
  }

  #pragma unroll
  for (int nt = 0; nt < 2; ++nt) {
    const int n = n0 + wn + nt*16 + l15;
    if (NMASK && n >= N) continue;
    const float bvs = bias[n];
    #pragma unroll
    for (int mt = 0; mt < 2; ++mt) {
      const int mr = m0 + wm + mt*16 + quad*4;
      #pragma unroll
      for (int r = 0; r < 4; ++r) {
        float v = acc[mt][nt][r] + bvs;
        if (RELU) v = fmaxf(v, 0.f);
        if (OUT_BF16) ((bf16*)C)[(size_t)(mr + r)*N + n] = (bf16)v;
        else          ((float*)C)[(size_t)(mr + r)*N + n] = v;
      }
    }
  }
}

// ---------------------------------------------------------------------------
// Fused GEMM + residual + LayerNorm:  x = LN(x + A@BT^T + bias)*g + be.
// M-tile 16, N=256, grid (M/16)=512.
// ---------------------------------------------------------------------------
__global__ __launch_bounds__(256) void gemm_ln(
    const bf16* __restrict__ A, const bf16* __restrict__ BT,
    const float* __restrict__ bias, const float* __restrict__ g,
    const float* __restrict__ be, bf16* xio, int K)
{
  __shared__ bf16 As[16*32];
  __shared__ bf16 Bs[256*32];
  __shared__ bf16 Xs[16][264];
  __shared__ float sums[4][16][2];

  const int tid  = threadIdx.x;
  const int lane = tid & 63, wave = tid >> 6;
  const int quad = lane >> 4, l15 = lane & 15;
  const int m0 = blockIdx.x * 16;
  const int wn = wave * 64;

  const bf16* a0 = A + (size_t)m0 * K;
  const int chs = SRC_CHS(tid);
  const int q8  = FRAG_Q8(quad, l15);

  f32x4 acc[4] = {};

  for (int k0 = 0; k0 < K; k0 += 32) {
    __syncthreads();
    if (wave == 0)
      load_lds16(a0 + (size_t)(lane >> 2)*K + k0 + SRC_CHS(lane), (char*)As);
    #pragma unroll
    for (int j = 0; j < 4; ++j)
      load_lds16(BT + (size_t)(64*j + (tid >> 2))*K + k0 + chs,
                 (char*)Bs + j*4096 + (size_t)wave*1024);
    __syncthreads();
    const bf16x8 af = *(const bf16x8*)(As + l15*32 + q8);
    #pragma unroll
    for (int nt = 0; nt < 4; ++nt) {
      const bf16x8 bfr = *(const bf16x8*)(Bs + (wn + nt*16 + l15)*32 + q8);
      acc[nt] = __builtin_amdgcn_mfma_f32_16x16x32_bf16(af, bfr, acc[nt], 0, 0, 0);
    }
  }

  {
    const int xr = tid >> 4, xc = (tid & 15) * 16;
    const bf16* src = xio + (size_t)(m0 + xr)*D_ + xc;
    *(bf16x8*)&Xs[xr][xc]     = *(const bf16x8*)src;
    *(bf16x8*)&Xs[xr][xc + 8] = *(const bf16x8*)(src + 8);
  }
  __syncthreads();

  float v[4][4];
  float bvs[4];
  #pragma unroll
  for (int nt = 0; nt < 4; ++nt) bvs[nt] = bias[wn + nt*16 + l15];
  #pragma unroll
  for (int r = 0; r < 4; ++r) {
    const int rr = quad*4 + r;
    float ls = 0.f, lq = 0.f;
    #pragma unroll
    for (int nt = 0; nt < 4; ++nt) {
      const float y = acc[nt][r] + bvs[nt];
      const float xv = b2f(*(const unsigned short*)&Xs[rr][wn + nt*16 + l15]);
      const float vv = xv + y;
      v[r][nt] = vv;
      ls += vv;
      lq += vv*vv;
    }
    ls = red_sum16(ls);
    lq = red_sum16(lq);
    if (l15 == 0) { sums[wave][rr][0] = ls; sums[wave][rr][1] = lq; }
  }
  __syncthreads();

  float gv[4], bev[4];
  #pragma unroll
  for (int nt = 0; nt < 4; ++nt) {
    gv[nt]  = g[wn + nt*16 + l15];
    bev[nt] = be[wn + nt*16 + l15];
  }
  #pragma unroll
  for (int r = 0; r < 4; ++r) {
    const int rr = quad*4 + r;
    const float ts = sums[0][rr][0] + sums[1][rr][0] + sums[2][rr][0] + sums[3][rr][0];
    const float tq = sums[0][rr][1] + sums[1][rr][1] + sums[2][rr][1] + sums[3][rr][1];
    const float mean = ts * (1.f/256.f);
    const float var  = tq * (1.f/256.f) - mean*mean;
    const float inv  = rsqrtf(var + 1e-5f);
    #pragma unroll
    for (int nt = 0; nt < 4; ++nt) {
      const bf16 o = (bf16)((v[r][nt] - mean)*inv*gv[nt] + bev[nt]);
      Xs[rr][wn + nt*16 + l15] = o;
    }
  }
  __syncthreads();

  {
    const int xr = tid >> 4, xc = (tid & 15) * 16;
    bf16* dst = xio + (size_t)(m0 + xr)*D_ + xc;
    *(bf16x8*)dst       = *(const bf16x8*)&Xs[xr][xc];
    *(bf16x8*)(dst + 8) = *(const bf16x8*)&Xs[xr][xc + 8];
  }
}

// ---------------------------------------------------------------------------
// SPLIT-K flash attention, causal, max-free exp2 softmax, transposed scores.
// grid (32, H, B): chunk = blockIdx.x>>4 splits each q-strip's key tiles in
// half; 8192 waves total for latency hiding.  Max-free softmax makes the
// combine exact: o = o0+o1, l = l0+l1 (no rescale).  Partials: po bf16,
// pl f32.  __launch_bounds__(256,8) caps VGPR at 64 -> 8 waves/SIMD.
// ---------------------------------------------------------------------------
#define PSTR 68
__global__ __launch_bounds__(256, 8) void attn_kernel(
    const bf16* __restrict__ qp, const bf16* __restrict__ kp,
    const bf16* __restrict__ vt, const int* __restrict__ tsl,
    bf16* __restrict__ po, float* __restrict__ pl)
{
  const int h = blockIdx.y, b = blockIdx.z;
  const int lane = threadIdx.x & 63, wave = threadIdx.x >> 6;
  const int quad = lane >> 4, l15 = lane & 15;
  const int c   = blockIdx.x >> 4;           // split-K chunk 0/1
  const int sid = (blockIdx.x & 15) + wave*16;
  const int q0 = sid*16;
  const int len = tsl[b];

  __shared__ bf16 Pl[4][16*PSTR];

  const size_t bh = (size_t)b*H_ + h;
  const bf16* qb = qp + bh*S_*DH_;
  const bf16* kb = kp + bh*S_*DH_;
  const bf16* vb = vt + bh*DH_*S_;

  const bf16x8 qf = *(const bf16x8*)(qb + (size_t)(q0 + l15)*DH_ + quad*8);

  float lacc = 0.f;
  f32x4 o0 = {0.f,0.f,0.f,0.f}, o1 = {0.f,0.f,0.f,0.f};

  bf16* pw = &Pl[wave][0];
  const int qr = q0 + l15;
  const bool full = (len >= S_);
  const int dt = sid >> 2;
  const int ntiles = dt + 1;
  const int c0e = (ntiles + 1) >> 1;         // chunk0 = [0,c0e), chunk1 = [c0e,ntiles)
  const int ts = c ? c0e : 0;
  const int te = c ? ntiles : c0e;

  for (int ks = ts; ks < te; ++ks) {
    const int k0 = ks*64;
    // transposed scores: C[m=key][n=qrow]
    f32x4 s[4];
    #pragma unroll
    for (int nt = 0; nt < 4; ++nt) {
      const bf16x8 kf = *(const bf16x8*)(kb + (size_t)(k0 + nt*16 + l15)*DH_ + quad*8);
      const f32x4 z = {0.f,0.f,0.f,0.f};
      s[nt] = __builtin_amdgcn_mfma_f32_16x16x32_bf16(kf, qf, z, 0, 0, 0);
    }
    // V frags (independent of s; loads overlap the exp phase)
    bf16x8 vf[4];
    #pragma unroll
    for (int kc = 0; kc < 2; ++kc) {
      vf[kc*2]   = *(const bf16x8*)(vb + (size_t)l15*S_      + k0 + kc*32 + quad*8);
      vf[kc*2+1] = *(const bf16x8*)(vb + (size_t)(16+l15)*S_ + k0 + kc*32 + quad*8);
    }
    // p = exp2(s) (mask on diagonal / short-len), pack 4 keys -> b64 write
    #pragma unroll
    for (int nt = 0; nt < 4; ++nt) {
      float p0, p1, p2, p3;
      if (full && ks < dt) {
        p0 = exp2f(s[nt][0]);
        p1 = exp2f(s[nt][1]);
        p2 = exp2f(s[nt][2]);
        p3 = exp2f(s[nt][3]);
      } else {
        const int kbase = k0 + nt*16 + quad*4;
        const bool okq = (qr < len);
        p0 = (okq && kbase+0 <= qr && kbase+0 < len) ? exp2f(s[nt][0]) : 0.f;
        p1 = (okq && kbase+1 <= qr && kbase+1 < len) ? exp2f(s[nt][1]) : 0.f;
        p2 = (okq && kbase+2 <= qr && kbase+2 < len) ? exp2f(s[nt][2]) : 0.f;
        p3 = (okq && kbase+3 <= qr && kbase+3 < len) ? exp2f(s[nt][3]) : 0.f;
      }
      lacc += (p0 + p1) + (p2 + p3);
      uint2 w;
      w.x = (unsigned)f2b(p0) | ((unsigned)f2b(p1) << 16);
      w.y = (unsigned)f2b(p2) | ((unsigned)f2b(p3) << 16);
      *(uint2*)((char*)pw + l15*(PSTR*2) + nt*32 + quad*8) = w;
    }
    asm volatile("s_waitcnt lgkmcnt(0)" ::: "memory");
    #pragma unroll
    for (int kc = 0; kc < 2; ++kc) {
      const bf16x8 pf = *(const bf16x8*)(pw + l15*PSTR + kc*32 + quad*8);
      o0 = __builtin_amdgcn_mfma_f32_16x16x32_bf16(pf, vf[kc*2],   o0, 0, 0, 0);
      o1 = __builtin_amdgcn_mfma_f32_16x16x32_bf16(pf, vf[kc*2+1], o1, 0, 0, 0);
    }
  }

  // l: after xor-16/32, every lane holds total l for qrow = l15
  float lt = lacc;
  lt += __shfl_xor(lt, 16);
  lt += __shfl_xor(lt, 32);

  // store partials (unnormalized): empty chunks store zeros
  bf16* pb = po + (((size_t)c*64 + bh)*S_ + q0)*DH_;
  #pragma unroll
  for (int r = 0; r < 4; ++r) {
    const int row = quad*4 + r;
    pb[(size_t)row*DH_ + l15]      = (bf16)o0[r];
    pb[(size_t)row*DH_ + 16 + l15] = (bf16)o1[r];
  }
  if (quad == 0)
    pl[((size_t)c*64 + bh)*S_ + q0 + l15] = lt;
}

// ---------------------------------------------------------------------------
// Combine split-K partials: aout[b][s][h*32+d] = (po0+po1)/(l0+l1).
// grid 1024, block 256: 262144 threads = 64 bh x 1024 rows x 4 dh-chunks.
// (r13 BUG: grid 128 only covered bh 0..7 -> batches 1..7 were garbage.)
// ---------------------------------------------------------------------------
__global__ void attn_combine(const bf16* __restrict__ po, const float* __restrict__ pl,
                             bf16* __restrict__ aout)
{
  const int t = blockIdx.x*256 + threadIdx.x;   // 0..262143
  const int dc  = t & 3;
  const int row = (t >> 2) & 1023;
  const int bh  = t >> 12;                      // 0..63
  const float l0 = pl[(size_t)bh*S_ + row];
  const float l1 = pl[(size_t)(64 + bh)*S_ + row];
  const float inv = 1.f / fmaxf(l0 + l1, 1e-30f);
  const bf16* p0 = po + ((size_t)bh*S_ + row)*DH_ + dc*8;
  const bf16* p1 = po + ((size_t)(64 + bh)*S_ + row)*DH_ + dc*8;
  const bf16x8 a = *(const bf16x8*)p0;
  const bf16x8 bb = *(const bf16x8*)p1;
  const int b = bh >> 3, h = bh & 7;
  bf16* dst = aout + ((size_t)b*S_ + row)*D_ + h*DH_ + dc*8;
  bf16x8 o;
  #pragma unroll
  for (int i = 0; i < 8; ++i)
    o[i] = (__bf16)(((float)a[i] + (float)bb[i]) * inv);
  *(bf16x8*)dst = o;
}

// ---------------------------------------------------------------------------
extern "C" void kernel_launch(void* const* d_in, const int* in_sizes, int n_in,
                              void* d_out, int out_size, void* d_ws, size_t ws_size,
                              hipStream_t stream)
{
  const int*   ids = (const int*)d_in[0];
  const int*   tsl = (const int*)d_in[1];
  const float* emb = (const float*)d_in[2];
  const float* Wq  = (const float*)d_in[3];
  const float* bq  = (const float*)d_in[4];
  const float* Wk  = (const float*)d_in[5];
  const float* bk  = (const float*)d_in[6];
  const float* Wv  = (const float*)d_in[7];
  const float* bv  = (const float*)d_in[8];
  const float* Wo  = (const float*)d_in[9];
  const float* bo  = (const float*)d_in[10];
  const float* W1  = (const float*)d_in[11];
  const float* b1  = (const float*)d_in[12];
  const float* W2  = (const float*)d_in[13];
  const float* b2  = (const float*)d_in[14];
  const float* g1  = (const float*)d_in[15];
  const float* be1 = (const float*)d_in[16];
  const float* g2  = (const float*)d_in[17];
  const float* be2 = (const float*)d_in[18];
  const float* Wc  = (const float*)d_in[19];
  const float* bc  = (const float*)d_in[20];

  if (ws_size < (size_t)40*1024*1024) return;

  char* p = (char*)d_ws;
  auto carve = [&](size_t bytes) { void* r = (void*)p; p += (bytes + 255) & ~(size_t)255; return r; };
  bf16*  x     = (bf16*) carve((size_t)M_*D_*2);
  char*  big   = (char*) carve((size_t)M_*DFF_*2);     // 16 MB: aout|po|pl, later ff1
  char*  pkbuf = (char*) carve((size_t)12*1024*1024);
  bf16*  WqkvT = (bf16*) carve((size_t)L_*768*256*2);
  bf16*  WoT   = (bf16*) carve((size_t)L_*65536*2);
  bf16*  W1T   = (bf16*) carve((size_t)L_*262144*2);
  bf16*  W2T   = (bf16*) carve((size_t)L_*262144*2);
  bf16*  WcT   = (bf16*) carve((size_t)128*256*2);
  float* bqkv  = (float*)carve((size_t)L_*768*4);

  bf16*  aout = (bf16*) big;                           // [0, 4 MB)
  bf16*  po   = (bf16*)(big + (size_t)4*1024*1024);    // [4, 12 MB): 2x64x1024x32 bf16
  float* pl   = (float*)(big + (size_t)12*1024*1024);  // [12, 12.5 MB)
  bf16*  ff1  = (bf16*) big;                           // reuses big after aout consumed
  bf16*  qp   = (bf16*)pkbuf;
  bf16*  kp   = (bf16*)(pkbuf + (size_t)4*1024*1024);
  bf16*  vt   = (bf16*)(pkbuf + (size_t)8*1024*1024);

  prep_t<<<dim3(32,32,26), dim3(32,8), 0, stream>>>(Wq,Wk,Wv,Wo,W1,W2,Wc,bq,bk,bv,
                                                    WqkvT,WoT,W1T,W2T,WcT,bqkv);
  embed_kernel<<<dim3(M_), 256, 0, stream>>>(ids, emb, x);

  for (int l = 0; l < L_; ++l) {
    gemm_qkv<<<dim3(64,12), 256, 0, stream>>>(
        x, WqkvT + (size_t)l*768*256, bqkv + l*768, qp, kp, vt);
    attn_kernel<<<dim3(32,8,8), 256, 0, stream>>>(qp, kp, vt, tsl, po, pl);
    attn_combine<<<dim3(1024), 256, 0, stream>>>(po, pl, aout);
    gemm_ln<<<dim3(512), 256, 0, stream>>>(
        aout, WoT + (size_t)l*65536, bo + l*256, g1 + l*256, be1 + l*256, x, 256);
    gemm_bt<true,true><<<dim3(64,16), 256, 0, stream>>>(
        x, W1T + (size_t)l*262144, b1 + l*1024, ff1, M_, 1024, 256);
    gemm_ln<<<dim3(512), 256, 0, stream>>>(
        ff1, W2T + (size_t)l*262144, b2 + l*256, g2 + l*256, be2 + l*256, x, 1024);
  }

  gemm_bt64<false,false,true><<<dim3(128,2), 256, 0, stream>>>(
      x, WcT, bc, (float*)d_out, M_, V_, 256);
}

// Round 15
// 458.021 us; speedup vs baseline: 1.0895x; 1.0895x over previous
//
#include <hip/hip_runtime.h>
#include <hip/hip_bf16.h>
#include <stdint.h>

#define B_   8
#define S_   1024
#define D_   256
#define H_   8
#define DH_  32
#define L_   4
#define V_   100
#define DFF_ 1024
#define M_   (B_*S_)   // 8192

using bf16 = __hip_bfloat16;
typedef __bf16 bf16x8 __attribute__((ext_vector_type(8)));
typedef float  f32x4  __attribute__((ext_vector_type(4)));

static __device__ __forceinline__ float b2f(unsigned short u) {
  union { unsigned int i; float f; } w; w.i = ((unsigned int)u) << 16; return w.f;
}
static __device__ __forceinline__ unsigned short f2b(float f) {
  bf16 h = (bf16)f; return *(unsigned short*)&h;
}

// async global->LDS DMA: 16B/lane, LDS dest = wave-uniform base + lane*16
static __device__ __forceinline__ void load_lds16(const void* g, void* l) {
  __builtin_amdgcn_global_load_lds((const __attribute__((address_space(1))) void*)g,
                                   (__attribute__((address_space(3))) void*)l,
                                   16, 0, 0);
}

// LDS bank swizzle (see r9): global-source chunk permutation, 2-way aliasing.
#define SRC_CHS(tid)  ((((tid) & 3) ^ (((tid) >> 3) & 3)) * 8)
#define FRAG_Q8(quad, l15)  (((quad) ^ (((l15) >> 1) & 3)) * 8)

// DPP cross-lane reductions over the 16-lane l15 group (== DPP row).
template<int CTRL>
static __device__ __forceinline__ float dppf(float v) {
  union { float f; int i; } a, r;
  a.f = v;
  r.i = __builtin_amdgcn_update_dpp(0, a.i, CTRL, 0xF, 0xF, true);
  return r.f;
}
static __device__ __forceinline__ float red_sum16(float v) {
  v += dppf<0xB1>(v);
  v += dppf<0x4E>(v);
  v += dppf<0x141>(v);
  v += dppf<0x140>(v);
  return v;
}

// ---------------------------------------------------------------------------
// Prep: weight transposes (z 0..24), fused qkv bias (z 25), AND the
// embedding+positional-encoding (z 26..33) — one dispatch for all setup.
// grid (32,32,34), block (32,8).
// ---------------------------------------------------------------------------
__global__ void prep_t(const float* __restrict__ Wq, const float* __restrict__ Wk,
                       const float* __restrict__ Wv, const float* __restrict__ Wo,
                       const float* __restrict__ W1, const float* __restrict__ W2,
                       const float* __restrict__ Wc,
                       const float* __restrict__ bq, const float* __restrict__ bk,
                       const float* __restrict__ bv,
                       const int* __restrict__ ids, const float* __restrict__ emb,
                       bf16* __restrict__ WqkvT, bf16* __restrict__ WoT,
                       bf16* __restrict__ W1T, bf16* __restrict__ W2T,
                       bf16* __restrict__ WcT, float* __restrict__ bqkv,
                       bf16* __restrict__ x)
{
  const int z = blockIdx.z;
  const int tid = threadIdx.y*32 + threadIdx.x;
  if (z >= 26) {                                 // embedding + sinusoidal PE
    const int bs = (z - 26)*1024 + blockIdx.y*32 + blockIdx.x;  // 0..8191
    const int d  = tid;                          // 0..255
    const int s  = bs & (S_-1);
    const int id = ids[bs];
    const int f  = (d < 128) ? (2*d) : (2*(d-128)+1);
    const float inv = powf(10000.f, -(float)f * (1.f/256.f));
    const float pe  = sinf((float)s * inv);
    x[(size_t)bs*D_ + d] = (bf16)(emb[(size_t)id*D_ + d] + pe);
    return;
  }
  if (z == 25) {                                 // fused qkv bias
    if (blockIdx.x || blockIdx.y) return;
    for (int i = tid; i < L_*768; i += 256) {
      const int l2 = i / 768, j = i % 768;
      const float* src = (j < 256) ? bq : (j < 512) ? bk : bv;
      bqkv[i] = src[l2*256 + (j & 255)];
    }
    return;
  }
  const float* src; bf16* dst; int R, C, Cd;
  if (z < 12) {
    const int l = z / 3, w = z % 3;
    src = ((w == 0) ? Wq : (w == 1) ? Wk : Wv) + (size_t)l*65536;
    R = 256; C = 256; Cd = 256;
    dst = WqkvT + (size_t)l*196608 + (size_t)w*65536;
  } else if (z < 16) {
    const int l = z - 12;
    src = Wo + (size_t)l*65536; R = 256; C = 256; Cd = 256;
    dst = WoT + (size_t)l*65536;
  } else if (z < 20) {
    const int l = z - 16;
    src = W1 + (size_t)l*262144; R = 256; C = 1024; Cd = 1024;
    dst = W1T + (size_t)l*262144;
  } else if (z < 24) {
    const int l = z - 20;
    src = W2 + (size_t)l*262144; R = 1024; C = 256; Cd = 256;
    dst = W2T + (size_t)l*262144;
  } else {
    src = Wc; R = 256; C = 100; Cd = 128;
    dst = WcT;
  }
  const int c0 = blockIdx.x*32, r0 = blockIdx.y*32;
  if (c0 >= Cd || r0 >= R) return;
  __shared__ float t[32][33];
  #pragma unroll
  for (int i = 0; i < 4; ++i) {
    const int r = r0 + threadIdx.y + i*8;
    const int c = c0 + threadIdx.x;
    t[threadIdx.y + i*8][threadIdx.x] = (r < R && c < C) ? src[(size_t)r*C + c] : 0.f;
  }
  __syncthreads();
  #pragma unroll
  for (int i = 0; i < 4; ++i) {
    const int c = c0 + threadIdx.y + i*8;
    const int r = r0 + threadIdx.x;
    if (c < Cd && r < R)
      dst[(size_t)c*R + r] = (bf16)t[threadIdx.x][threadIdx.y + i*8];
  }
}

// ---------------------------------------------------------------------------
// QKV GEMM with packed epilogue -> qp[bh][s][32] (PRE-SCALED by
// log2(e)/sqrt(dh) for the exp2-based softmax), kp, vt[bh][d][s].
// ---------------------------------------------------------------------------
__global__ __launch_bounds__(256) void gemm_qkv(
    const bf16* __restrict__ A, const bf16* __restrict__ BT,
    const float* __restrict__ bias,
    bf16* __restrict__ qp, bf16* __restrict__ kp, bf16* __restrict__ vt)
{
  __shared__ bf16 As[128*32];
  __shared__ bf16 Bs[64*32];
  __shared__ bf16 Vs[64][136];
  const int tid  = threadIdx.x;
  const int lane = tid & 63, wave = tid >> 6;
  const int quad = lane >> 4, l15 = lane & 15;
  const int m0 = blockIdx.x * 128;
  const int n0 = blockIdx.y * 64;
  const int wm = (wave & 1) * 64;
  const int wn = (wave >> 1) * 32;
  const int K = 256;

  const bf16* a0 = A  + (size_t)m0 * K;
  const bf16* b0 = BT + (size_t)n0 * K;
  const int row = tid >> 2;
  const int chs = SRC_CHS(tid);
  const int q8  = FRAG_Q8(quad, l15);

  f32x4 acc[4][2] = {};

  for (int k0 = 0; k0 < K; k0 += 32) {
    __syncthreads();
    load_lds16(a0 + (size_t)row*K      + k0 + chs, (char*)As + (size_t)wave*1024);
    load_lds16(a0 + (size_t)(row+64)*K + k0 + chs, (char*)As + 4096 + (size_t)wave*1024);
    load_lds16(b0 + (size_t)row*K      + k0 + chs, (char*)Bs + (size_t)wave*1024);
    __syncthreads();
    bf16x8 af[4], bfr[2];
    #pragma unroll
    for (int mt = 0; mt < 4; ++mt)
      af[mt] = *(const bf16x8*)(As + (wm + mt*16 + l15)*32 + q8);
    #pragma unroll
    for (int nt = 0; nt < 2; ++nt)
      bfr[nt] = *(const bf16x8*)(Bs + (wn + nt*16 + l15)*32 + q8);
    #pragma unroll
    for (int mt = 0; mt < 4; ++mt)
      #pragma unroll
      for (int nt = 0; nt < 2; ++nt)
        acc[mt][nt] = __builtin_amdgcn_mfma_f32_16x16x32_bf16(af[mt], bfr[nt], acc[mt][nt], 0, 0, 0);
  }

  const int seg = n0 >> 8;            // 0=Q, 1=K, 2=V
  const int b  = m0 >> 10;
  const int s0 = m0 & 1023;

  if (seg < 2) {
    bf16* dst = seg ? kp : qp;
    // Q pre-scale: 1/sqrt(32) * log2(e)  (softmax uses exp2)
    const float sc = seg ? 1.f : (0.17677669529663687f * 1.4426950408889634f);
    #pragma unroll
    for (int nt = 0; nt < 2; ++nt) {
      const int n  = n0 + wn + nt*16 + l15;
      const int nn = n & 255;
      const int h = nn >> 5, d = nn & 31;
      const float bvs = bias[n];
      bf16* hb = dst + (((size_t)b*H_ + h)*S_)*DH_ + d;
      #pragma unroll
      for (int mt = 0; mt < 4; ++mt) {
        const int ml = wm + mt*16 + quad*4;
        #pragma unroll
        for (int r = 0; r < 4; ++r)
          hb[(size_t)(s0 + ml + r)*DH_] = (bf16)((acc[mt][nt][r] + bvs) * sc);
      }
    }
  } else {
    #pragma unroll
    for (int nt = 0; nt < 2; ++nt) {
      const int nl = wn + nt*16 + l15;
      const float bvs = bias[n0 + nl];
      #pragma unroll
      for (int mt = 0; mt < 4; ++mt) {
        const int ml = wm + mt*16 + quad*4;
        #pragma unroll
        for (int r = 0; r < 4; ++r)
          Vs[nl][ml + r] = (bf16)(acc[mt][nt][r] + bvs);
      }
    }
    __syncthreads();
    #pragma unroll
    for (int t = 0; t < 2; ++t) {
      const int vrow = (tid >> 3) + 32*t;
      const int soff = (tid & 7) * 16;
      const int nn = (n0 + vrow) & 255;
      const int h = nn >> 5, d = nn & 31;
      bf16* dst = vt + (((size_t)b*H_ + h)*DH_ + d)*S_ + s0 + soff;
      *(bf16x8*)dst       = *(const bf16x8*)&Vs[vrow][soff];
      *(bf16x8*)(dst + 8) = *(const bf16x8*)&Vs[vrow][soff + 8];
    }
  }
}

// ---------------------------------------------------------------------------
// Generic GEMM 128x64 tile (bias + optional relu) — used for FF1.
// ---------------------------------------------------------------------------
template<bool RELU, bool OUT_BF16>
__global__ __launch_bounds__(256) void gemm_bt(
    const bf16* __restrict__ A, const bf16* __restrict__ BT,
    const float* __restrict__ bias, void* __restrict__ C,
    int M, int N, int K)
{
  __shared__ bf16 As[128*32];
  __shared__ bf16 Bs[64*32];
  const int tid  = threadIdx.x;
  const int lane = tid & 63, wave = tid >> 6;
  const int quad = lane >> 4, l15 = lane & 15;
  const int m0 = blockIdx.x * 128;
  const int n0 = blockIdx.y * 64;
  const int wm = (wave & 1) * 64;
  const int wn = (wave >> 1) * 32;

  const bf16* a0 = A  + (size_t)m0 * K;
  const bf16* b0 = BT + (size_t)n0 * K;
  const int row = tid >> 2;
  const int chs = SRC_CHS(tid);
  const int q8  = FRAG_Q8(quad, l15);

  f32x4 acc[4][2] = {};

  for (int k0 = 0; k0 < K; k0 += 32) {
    __syncthreads();
    load_lds16(a0 + (size_t)row*K      + k0 + chs, (char*)As + (size_t)wave*1024);
    load_lds16(a0 + (size_t)(row+64)*K + k0 + chs, (char*)As + 4096 + (size_t)wave*1024);
    load_lds16(b0 + (size_t)row*K      + k0 + chs, (char*)Bs + (size_t)wave*1024);
    __syncthreads();
    bf16x8 af[4], bfr[2];
    #pragma unroll
    for (int mt = 0; mt < 4; ++mt)
      af[mt] = *(const bf16x8*)(As + (wm + mt*16 + l15)*32 + q8);
    #pragma unroll
    for (int nt = 0; nt < 2; ++nt)
      bfr[nt] = *(const bf16x8*)(Bs + (wn + nt*16 + l15)*32 + q8);
    #pragma unroll
    for (int mt = 0; mt < 4; ++mt)
      #pragma unroll
      for (int nt = 0; nt < 2; ++nt)
        acc[mt][nt] = __builtin_amdgcn_mfma_f32_16x16x32_bf16(af[mt], bfr[nt], acc[mt][nt], 0, 0, 0);
  }

  #pragma unroll
  for (int nt = 0; nt < 2; ++nt) {
    const int n = n0 + wn + nt*16 + l15;
    const float bvs = bias[n];
    #pragma unroll
    for (int mt = 0; mt < 4; ++mt) {
      const int mr = m0 + wm + mt*16 + quad*4;
      #pragma unroll
      for (int r = 0; r < 4; ++r) {
        float v = acc[mt][nt][r] + bvs;
        if (RELU) v = fmaxf(v, 0.f);
        if (OUT_BF16) ((bf16*)C)[(size_t)(mr + r)*N + n] = (bf16)v;
        else          ((float*)C)[(size_t)(mr + r)*N + n] = v;
      }
    }
  }
}

// ---------------------------------------------------------------------------
// GEMM 64x64 tile — classifier (NMASK).
// ---------------------------------------------------------------------------
template<bool RELU, bool OUT_BF16, bool NMASK>
__global__ __launch_bounds__(256) void gemm_bt64(
    const bf16* __restrict__ A, const bf16* __restrict__ BT,
    const float* __restrict__ bias, void* __restrict__ C,
    int M, int N, int K)
{
  __shared__ bf16 As[64*32];
  __shared__ bf16 Bs[64*32];
  const int tid  = threadIdx.x;
  const int lane = tid & 63, wave = tid >> 6;
  const int quad = lane >> 4, l15 = lane & 15;
  const int m0 = blockIdx.x * 64;
  const int n0 = blockIdx.y * 64;
  const int wm = (wave & 1) * 32;
  const int wn = (wave >> 1) * 32;

  const bf16* a0 = A  + (size_t)m0 * K;
  const bf16* b0 = BT + (size_t)n0 * K;
  const int row = tid >> 2;
  const int chs = SRC_CHS(tid);
  const int q8  = FRAG_Q8(quad, l15);

  f32x4 acc[2][2] = {};

  for (int k0 = 0; k0 < K; k0 += 32) {
    __syncthreads();
    load_lds16(a0 + (size_t)row*K + k0 + chs, (char*)As + (size_t)wave*1024);
    load_lds16(b0 + (size_t)row*K + k0 + chs, (char*)Bs + (size_t)wave*1024);
    __syncthreads();
    bf16x8 af[2], bfr[2];
    #pragma unroll
    for (int mt = 0; mt < 2; ++mt)
      af[mt] = *(const bf16x8*)(As + (wm + mt*16 + l15)*32 + q8);
    #pragma unroll
    for (int nt = 0; nt < 2; ++nt)
      bfr[nt] = *(const bf16x8*)(Bs + (wn + nt*16 + l15)*32 + q8);
    #pragma unroll
    for (int mt = 0; mt < 2; ++mt)
      #pragma unroll
      for (int nt = 0; nt < 2; ++nt)
        acc[mt][nt] = __builtin_amdgcn_mfma_f32_16x16x32_bf16(af[mt], bfr[nt], acc[mt][nt], 0, 0, 0);
  }

  #pragma unroll
  for (int nt = 0; nt < 2; ++nt) {
    const int n = n0 + wn + nt*16 + l15;
    if (NMASK && n >= N) continue;
    const float bvs = bias[n];
    #pragma unroll
    for (int mt = 0; mt < 2; ++mt) {
      const int mr = m0 + wm + mt*16 + quad*4;
      #pragma unroll
      for (int r = 0; r < 4; ++r) {
        float v = acc[mt][nt][r] + bvs;
        if (RELU) v = fmaxf(v, 0.f);
        if (OUT_BF16) ((bf16*)C)[(size_t)(mr + r)*N + n] = (bf16)v;
        else          ((float*)C)[(size_t)(mr + r)*N + n] = v;
      }
    }
  }
}

// ---------------------------------------------------------------------------
// Fused GEMM + residual + LayerNorm:  x = LN(x + A@BT^T + bias)*g + be.
// M-tile 16, N=256, grid (M/16)=512.
// ---------------------------------------------------------------------------
__global__ __launch_bounds__(256) void gemm_ln(
    const bf16* __restrict__ A, const bf16* __restrict__ BT,
    const float* __restrict__ bias, const float* __restrict__ g,
    const float* __restrict__ be, bf16* xio, int K)
{
  __shared__ bf16 As[16*32];
  __shared__ bf16 Bs[256*32];
  __shared__ bf16 Xs[16][264];
  __shared__ float sums[4][16][2];

  const int tid  = threadIdx.x;
  const int lane = tid & 63, wave = tid >> 6;
  const int quad = lane >> 4, l15 = lane & 15;
  const int m0 = blockIdx.x * 16;
  const int wn = wave * 64;

  const bf16* a0 = A + (size_t)m0 * K;
  const int chs = SRC_CHS(tid);
  const int q8  = FRAG_Q8(quad, l15);

  f32x4 acc[4] = {};

  for (int k0 = 0; k0 < K; k0 += 32) {
    __syncthreads();
    if (wave == 0)
      load_lds16(a0 + (size_t)(lane >> 2)*K + k0 + SRC_CHS(lane), (char*)As);
    #pragma unroll
    for (int j = 0; j < 4; ++j)
      load_lds16(BT + (size_t)(64*j + (tid >> 2))*K + k0 + chs,
                 (char*)Bs + j*4096 + (size_t)wave*1024);
    __syncthreads();
    const bf16x8 af = *(const bf16x8*)(As + l15*32 + q8);
    #pragma unroll
    for (int nt = 0; nt < 4; ++nt) {
      const bf16x8 bfr = *(const bf16x8*)(Bs + (wn + nt*16 + l15)*32 + q8);
      acc[nt] = __builtin_amdgcn_mfma_f32_16x16x32_bf16(af, bfr, acc[nt], 0, 0, 0);
    }
  }

  {
    const int xr = tid >> 4, xc = (tid & 15) * 16;
    const bf16* src = xio + (size_t)(m0 + xr)*D_ + xc;
    *(bf16x8*)&Xs[xr][xc]     = *(const bf16x8*)src;
    *(bf16x8*)&Xs[xr][xc + 8] = *(const bf16x8*)(src + 8);
  }
  __syncthreads();

  float v[4][4];
  float bvs[4];
  #pragma unroll
  for (int nt = 0; nt < 4; ++nt) bvs[nt] = bias[wn + nt*16 + l15];
  #pragma unroll
  for (int r = 0; r < 4; ++r) {
    const int rr = quad*4 + r;
    float ls = 0.f, lq = 0.f;
    #pragma unroll
    for (int nt = 0; nt < 4; ++nt) {
      const float y = acc[nt][r] + bvs[nt];
      const float xv = b2f(*(const unsigned short*)&Xs[rr][wn + nt*16 + l15]);
      const float vv = xv + y;
      v[r][nt] = vv;
      ls += vv;
      lq += vv*vv;
    }
    ls = red_sum16(ls);
    lq = red_sum16(lq);
    if (l15 == 0) { sums[wave][rr][0] = ls; sums[wave][rr][1] = lq; }
  }
  __syncthreads();

  float gv[4], bev[4];
  #pragma unroll
  for (int nt = 0; nt < 4; ++nt) {
    gv[nt]  = g[wn + nt*16 + l15];
    bev[nt] = be[wn + nt*16 + l15];
  }
  #pragma unroll
  for (int r = 0; r < 4; ++r) {
    const int rr = quad*4 + r;
    const float ts = sums[0][rr][0] + sums[1][rr][0] + sums[2][rr][0] + sums[3][rr][0];
    const float tq = sums[0][rr][1] + sums[1][rr][1] + sums[2][rr][1] + sums[3][rr][1];
    const float mean = ts * (1.f/256.f);
    const float var  = tq * (1.f/256.f) - mean*mean;
    const float inv  = rsqrtf(var + 1e-5f);
    #pragma unroll
    for (int nt = 0; nt < 4; ++nt) {
      const bf16 o = (bf16)((v[r][nt] - mean)*inv*gv[nt] + bev[nt]);
      Xs[rr][wn + nt*16 + l15] = o;
    }
  }
  __syncthreads();

  {
    const int xr = tid >> 4, xc = (tid & 15) * 16;
    bf16* dst = xio + (size_t)(m0 + xr)*D_ + xc;
    *(bf16x8*)dst       = *(const bf16x8*)&Xs[xr][xc];
    *(bf16x8*)(dst + 8) = *(const bf16x8*)&Xs[xr][xc + 8];
  }
}

// ---------------------------------------------------------------------------
// Flash attention, causal — r12 form (best measured): max-free exp2 softmax,
// transposed score MFMA, K prefetch, single dispatch, grid (16,H,B).
// ---------------------------------------------------------------------------
#define PSTR 68
__global__ __launch_bounds__(256) void attn_kernel(
    const bf16* __restrict__ qp, const bf16* __restrict__ kp,
    const bf16* __restrict__ vt, const int* __restrict__ tsl,
    bf16* __restrict__ out)
{
  const int h = blockIdx.y, b = blockIdx.z;
  const int lane = threadIdx.x & 63, wave = threadIdx.x >> 6;
  const int quad = lane >> 4, l15 = lane & 15;
  const int sid = blockIdx.x + wave*16;
  const int q0 = sid*16;
  const int len = tsl[b];

  __shared__ bf16 Pl[4][16*PSTR];

  const size_t bh = (size_t)b*H_ + h;
  const bf16* qb = qp + bh*S_*DH_;
  const bf16* kb = kp + bh*S_*DH_;
  const bf16* vb = vt + bh*DH_*S_;

  const bf16x8 qf = *(const bf16x8*)(qb + (size_t)(q0 + l15)*DH_ + quad*8);

  float lacc = 0.f;
  f32x4 o0 = {0.f,0.f,0.f,0.f}, o1 = {0.f,0.f,0.f,0.f};

  bf16* pw = &Pl[wave][0];
  const int qr = q0 + l15;
  const bool full = (len >= S_);
  const int dt = sid >> 2;

  bf16x8 kf[4];
  #pragma unroll
  for (int nt = 0; nt < 4; ++nt)
    kf[nt] = *(const bf16x8*)(kb + (size_t)(nt*16 + l15)*DH_ + quad*8);

  for (int ks = 0; ks <= dt; ++ks) {
    const int k0 = ks*64;
    bf16x8 vf[4];
    #pragma unroll
    for (int kc = 0; kc < 2; ++kc) {
      vf[kc*2]   = *(const bf16x8*)(vb + (size_t)l15*S_      + k0 + kc*32 + quad*8);
      vf[kc*2+1] = *(const bf16x8*)(vb + (size_t)(16+l15)*S_ + k0 + kc*32 + quad*8);
    }
    f32x4 s[4];
    #pragma unroll
    for (int nt = 0; nt < 4; ++nt) {
      const f32x4 z = {0.f,0.f,0.f,0.f};
      s[nt] = __builtin_amdgcn_mfma_f32_16x16x32_bf16(kf[nt], qf, z, 0, 0, 0);
    }
    bf16x8 kn[4];
    if (ks < dt) {
      const int k1 = k0 + 64;
      #pragma unroll
      for (int nt = 0; nt < 4; ++nt)
        kn[nt] = *(const bf16x8*)(kb + (size_t)(k1 + nt*16 + l15)*DH_ + quad*8);
    }
    #pragma unroll
    for (int nt = 0; nt < 4; ++nt) {
      float p0, p1, p2, p3;
      if (full && ks < dt) {
        p0 = exp2f(s[nt][0]);
        p1 = exp2f(s[nt][1]);
        p2 = exp2f(s[nt][2]);
        p3 = exp2f(s[nt][3]);
      } else {
        const int kbase = k0 + nt*16 + quad*4;
        const bool okq = (qr < len);
        p0 = (okq && kbase+0 <= qr && kbase+0 < len) ? exp2f(s[nt][0]) : 0.f;
        p1 = (okq && kbase+1 <= qr && kbase+1 < len) ? exp2f(s[nt][1]) : 0.f;
        p2 = (okq && kbase+2 <= qr && kbase+2 < len) ? exp2f(s[nt][2]) : 0.f;
        p3 = (okq && kbase+3 <= qr && kbase+3 < len) ? exp2f(s[nt][3]) : 0.f;
      }
      lacc += (p0 + p1) + (p2 + p3);
      uint2 w;
      w.x = (unsigned)f2b(p0) | ((unsigned)f2b(p1) << 16);
      w.y = (unsigned)f2b(p2) | ((unsigned)f2b(p3) << 16);
      *(uint2*)((char*)pw + l15*(PSTR*2) + nt*32 + quad*8) = w;
    }
    asm volatile("s_waitcnt lgkmcnt(0)" ::: "memory");
    #pragma unroll
    for (int kc = 0; kc < 2; ++kc) {
      const bf16x8 pf = *(const bf16x8*)(pw + l15*PSTR + kc*32 + quad*8);
      o0 = __builtin_amdgcn_mfma_f32_16x16x32_bf16(pf, vf[kc*2],   o0, 0, 0, 0);
      o1 = __builtin_amdgcn_mfma_f32_16x16x32_bf16(pf, vf[kc*2+1], o1, 0, 0, 0);
    }
    if (ks < dt) {
      #pragma unroll
      for (int nt = 0; nt < 4; ++nt) kf[nt] = kn[nt];
    }
  }

  float lt = lacc;
  lt += __shfl_xor(lt, 16);
  lt += __shfl_xor(lt, 32);

  bf16* ob = out + (size_t)b*S_*D_ + h*DH_;
  #pragma unroll
  for (int r = 0; r < 4; ++r) {
    const float lr = __shfl(lt, (lane & 48) | (quad*4 + r));
    const float inv = 1.f / fmaxf(lr, 1e-30f);
    const size_t rowoff = (size_t)(q0 + quad*4 + r)*D_;
    ob[rowoff + l15]      = (bf16)(o0[r]*inv);
    ob[rowoff + 16 + l15] = (bf16)(o1[r]*inv);
  }
}

// ---------------------------------------------------------------------------
extern "C" void kernel_launch(void* const* d_in, const int* in_sizes, int n_in,
                              void* d_out, int out_size, void* d_ws, size_t ws_size,
                              hipStream_t stream)
{
  const int*   ids = (const int*)d_in[0];
  const int*   tsl = (const int*)d_in[1];
  const float* emb = (const float*)d_in[2];
  const float* Wq  = (const float*)d_in[3];
  const float* bq  = (const float*)d_in[4];
  const float* Wk  = (const float*)d_in[5];
  const float* bk  = (const float*)d_in[6];
  const float* Wv  = (const float*)d_in[7];
  const float* bv  = (const float*)d_in[8];
  const float* Wo  = (const float*)d_in[9];
  const float* bo  = (const float*)d_in[10];
  const float* W1  = (const float*)d_in[11];
  const float* b1  = (const float*)d_in[12];
  const float* W2  = (const float*)d_in[13];
  const float* b2  = (const float*)d_in[14];
  const float* g1  = (const float*)d_in[15];
  const float* be1 = (const float*)d_in[16];
  const float* g2  = (const float*)d_in[17];
  const float* be2 = (const float*)d_in[18];
  const float* Wc  = (const float*)d_in[19];
  const float* bc  = (const float*)d_in[20];

  if (ws_size < (size_t)40*1024*1024) return;

  char* p = (char*)d_ws;
  auto carve = [&](size_t bytes) { void* r = (void*)p; p += (bytes + 255) & ~(size_t)255; return r; };
  bf16*  x     = (bf16*) carve((size_t)M_*D_*2);
  char*  big   = (char*) carve((size_t)M_*DFF_*2);
  char*  pkbuf = (char*) carve((size_t)12*1024*1024);
  bf16*  WqkvT = (bf16*) carve((size_t)L_*768*256*2);
  bf16*  WoT   = (bf16*) carve((size_t)L_*65536*2);
  bf16*  W1T   = (bf16*) carve((size_t)L_*262144*2);
  bf16*  W2T   = (bf16*) carve((size_t)L_*262144*2);
  bf16*  WcT   = (bf16*) carve((size_t)128*256*2);
  float* bqkv  = (float*)carve((size_t)L_*768*4);

  bf16*  aout = (bf16*)big;
  bf16*  ff1  = (bf16*)big;
  bf16*  qp   = (bf16*)pkbuf;
  bf16*  kp   = (bf16*)(pkbuf + (size_t)4*1024*1024);
  bf16*  vt   = (bf16*)(pkbuf + (size_t)8*1024*1024);

  prep_t<<<dim3(32,32,34), dim3(32,8), 0, stream>>>(Wq,Wk,Wv,Wo,W1,W2,Wc,bq,bk,bv,
                                                    ids, emb,
                                                    WqkvT,WoT,W1T,W2T,WcT,bqkv, x);

  for (int l = 0; l < L_; ++l) {
    gemm_qkv<<<dim3(64,12), 256, 0, stream>>>(
        x, WqkvT + (size_t)l*768*256, bqkv + l*768, qp, kp, vt);
    attn_kernel<<<dim3(16,8,8), 256, 0, stream>>>(qp, kp, vt, tsl, aout);
    gemm_ln<<<dim3(512), 256, 0, stream>>>(
        aout, WoT + (size_t)l*65536, bo + l*256, g1 + l*256, be1 + l*256, x, 256);
    gemm_bt<true,true><<<dim3(64,16), 256, 0, stream>>>(
        x, W1T + (size_t)l*262144, b1 + l*1024, ff1, M_, 1024, 256);
    gemm_ln<<<dim3(512), 256, 0, stream>>>(
        ff1, W2T + (size_t)l*262144, b2 + l*256, g2 + l*256, be2 + l*256, x, 1024);
  }

  gemm_bt64<false,false,true><<<dim3(128,2), 256, 0, stream>>>(
      x, WcT, bc, (float*)d_out, M_, V_, 256);
}

// Round 16
// 425.025 us; speedup vs baseline: 1.1741x; 1.0776x over previous
//
#include <hip/hip_runtime.h>
#include <hip/hip_bf16.h>
#include <stdint.h>

#define B_   8
#define S_   1024
#define D_   256
#define H_   8
#define DH_  32
#define L_   4
#define V_   100
#define DFF_ 1024
#define M_   (B_*S_)   // 8192

using bf16 = __hip_bfloat16;
typedef __bf16 bf16x8 __attribute__((ext_vector_type(8)));
typedef float  f32x4  __attribute__((ext_vector_type(4)));

static __device__ __forceinline__ float b2f(unsigned short u) {
  union { unsigned int i; float f; } w; w.i = ((unsigned int)u) << 16; return w.f;
}
static __device__ __forceinline__ unsigned short f2b(float f) {
  bf16 h = (bf16)f; return *(unsigned short*)&h;
}

// async global->LDS DMA: 16B/lane, LDS dest = wave-uniform base + lane*16
static __device__ __forceinline__ void load_lds16(const void* g, void* l) {
  __builtin_amdgcn_global_load_lds((const __attribute__((address_space(1))) void*)g,
                                   (__attribute__((address_space(3))) void*)l,
                                   16, 0, 0);
}

// BK=32 swizzle (classifier only)
#define SRC_CHS(tid)  ((((tid) & 3) ^ (((tid) >> 3) & 3)) * 8)
#define FRAG_Q8(quad, l15)  (((quad) ^ (((l15) >> 1) & 3)) * 8)

// BK=64 swizzle: chunk c of row r stored at physical chunk c ^ (r&7).
// Staging thread (row=tid>>3, ch=tid&7) fetches global chunk ch^(row&7).
// Frag read of logical chunk qc for row r: physical chunk qc^(r&7); all tile
// row bases are multiples of 16 so r&7 == l15&7.
#define GCH64(tid)  ((((tid) & 7) ^ (((tid) >> 3) & 7)) * 8)
#define FQ64(kh, quad, l15)  (((((kh)*4 + (quad)) ^ ((l15) & 7))) * 8)

// DPP cross-lane reductions over the 16-lane l15 group (== DPP row).
template<int CTRL>
static __device__ __forceinline__ float dppf(float v) {
  union { float f; int i; } a, r;
  a.f = v;
  r.i = __builtin_amdgcn_update_dpp(0, a.i, CTRL, 0xF, 0xF, true);
  return r.f;
}
static __device__ __forceinline__ float red_sum16(float v) {
  v += dppf<0xB1>(v);
  v += dppf<0x4E>(v);
  v += dppf<0x141>(v);
  v += dppf<0x140>(v);
  return v;
}

// ---------------------------------------------------------------------------
// Prep: weight transposes (z 0..24), fused qkv bias (z 25), embedding+PE
// (z 26..33).  grid (32,32,34), block (32,8).
// ---------------------------------------------------------------------------
__global__ void prep_t(const float* __restrict__ Wq, const float* __restrict__ Wk,
                       const float* __restrict__ Wv, const float* __restrict__ Wo,
                       const float* __restrict__ W1, const float* __restrict__ W2,
                       const float* __restrict__ Wc,
                       const float* __restrict__ bq, const float* __restrict__ bk,
                       const float* __restrict__ bv,
                       const int* __restrict__ ids, const float* __restrict__ emb,
                       bf16* __restrict__ WqkvT, bf16* __restrict__ WoT,
                       bf16* __restrict__ W1T, bf16* __restrict__ W2T,
                       bf16* __restrict__ WcT, float* __restrict__ bqkv,
                       bf16* __restrict__ x)
{
  const int z = blockIdx.z;
  const int tid = threadIdx.y*32 + threadIdx.x;
  if (z >= 26) {                                 // embedding + sinusoidal PE
    const int bs = (z - 26)*1024 + blockIdx.y*32 + blockIdx.x;  // 0..8191
    const int d  = tid;
    const int s  = bs & (S_-1);
    const int id = ids[bs];
    const int f  = (d < 128) ? (2*d) : (2*(d-128)+1);
    const float inv = powf(10000.f, -(float)f * (1.f/256.f));
    const float pe  = sinf((float)s * inv);
    x[(size_t)bs*D_ + d] = (bf16)(emb[(size_t)id*D_ + d] + pe);
    return;
  }
  if (z == 25) {                                 // fused qkv bias
    if (blockIdx.x || blockIdx.y) return;
    for (int i = tid; i < L_*768; i += 256) {
      const int l2 = i / 768, j = i % 768;
      const float* src = (j < 256) ? bq : (j < 512) ? bk : bv;
      bqkv[i] = src[l2*256 + (j & 255)];
    }
    return;
  }
  const float* src; bf16* dst; int R, C, Cd;
  if (z < 12) {
    const int l = z / 3, w = z % 3;
    src = ((w == 0) ? Wq : (w == 1) ? Wk : Wv) + (size_t)l*65536;
    R = 256; C = 256; Cd = 256;
    dst = WqkvT + (size_t)l*196608 + (size_t)w*65536;
  } else if (z < 16) {
    const int l = z - 12;
    src = Wo + (size_t)l*65536; R = 256; C = 256; Cd = 256;
    dst = WoT + (size_t)l*65536;
  } else if (z < 20) {
    const int l = z - 16;
    src = W1 + (size_t)l*262144; R = 256; C = 1024; Cd = 1024;
    dst = W1T + (size_t)l*262144;
  } else if (z < 24) {
    const int l = z - 20;
    src = W2 + (size_t)l*262144; R = 1024; C = 256; Cd = 256;
    dst = W2T + (size_t)l*262144;
  } else {
    src = Wc; R = 256; C = 100; Cd = 128;
    dst = WcT;
  }
  const int c0 = blockIdx.x*32, r0 = blockIdx.y*32;
  if (c0 >= Cd || r0 >= R) return;
  __shared__ float t[32][33];
  #pragma unroll
  for (int i = 0; i < 4; ++i) {
    const int r = r0 + threadIdx.y + i*8;
    const int c = c0 + threadIdx.x;
    t[threadIdx.y + i*8][threadIdx.x] = (r < R && c < C) ? src[(size_t)r*C + c] : 0.f;
  }
  __syncthreads();
  #pragma unroll
  for (int i = 0; i < 4; ++i) {
    const int c = c0 + threadIdx.y + i*8;
    const int r = r0 + threadIdx.x;
    if (c < Cd && r < R)
      dst[(size_t)c*R + r] = (bf16)t[threadIdx.x][threadIdx.y + i*8];
  }
}

// ---------------------------------------------------------------------------
// QKV GEMM, BK=64, packed epilogue -> qp (pre-scaled), kp, vt[bh][d][s].
// 128x64 tile, grid (64,12).  LDS: As 16K + Bs 8K + Vs 17K = 41K.
// ---------------------------------------------------------------------------
__global__ __launch_bounds__(256) void gemm_qkv(
    const bf16* __restrict__ A, const bf16* __restrict__ BT,
    const float* __restrict__ bias,
    bf16* __restrict__ qp, bf16* __restrict__ kp, bf16* __restrict__ vt)
{
  __shared__ bf16 As[128*64];
  __shared__ bf16 Bs[64*64];
  __shared__ bf16 Vs[64][136];
  const int tid  = threadIdx.x;
  const int lane = tid & 63, wave = tid >> 6;
  const int quad = lane >> 4, l15 = lane & 15;
  const int m0 = blockIdx.x * 128;
  const int n0 = blockIdx.y * 64;
  const int wm = (wave & 1) * 64;
  const int wn = (wave >> 1) * 32;
  const int K = 256;

  const bf16* a0 = A  + (size_t)m0 * K;
  const bf16* b0 = BT + (size_t)n0 * K;
  const int row32 = tid >> 3;
  const int gch   = GCH64(tid);
  const int l7    = l15 & 7;

  f32x4 acc[4][2] = {};

  for (int k0 = 0; k0 < K; k0 += 64) {
    __syncthreads();
    #pragma unroll
    for (int i = 0; i < 4; ++i)
      load_lds16(a0 + (size_t)(32*i + row32)*K + k0 + gch,
                 (char*)As + i*4096 + (size_t)wave*1024);
    #pragma unroll
    for (int i = 0; i < 2; ++i)
      load_lds16(b0 + (size_t)(32*i + row32)*K + k0 + gch,
                 (char*)Bs + i*4096 + (size_t)wave*1024);
    __syncthreads();
    #pragma unroll
    for (int kh = 0; kh < 2; ++kh) {
      const int fq = (((kh*4 + quad) ^ l7)) * 8;
      bf16x8 af[4], bfr[2];
      #pragma unroll
      for (int mt = 0; mt < 4; ++mt)
        af[mt] = *(const bf16x8*)(As + (wm + mt*16 + l15)*64 + fq);
      #pragma unroll
      for (int nt = 0; nt < 2; ++nt)
        bfr[nt] = *(const bf16x8*)(Bs + (wn + nt*16 + l15)*64 + fq);
      #pragma unroll
      for (int mt = 0; mt < 4; ++mt)
        #pragma unroll
        for (int nt = 0; nt < 2; ++nt)
          acc[mt][nt] = __builtin_amdgcn_mfma_f32_16x16x32_bf16(af[mt], bfr[nt], acc[mt][nt], 0, 0, 0);
    }
  }

  const int seg = n0 >> 8;            // 0=Q, 1=K, 2=V
  const int b  = m0 >> 10;
  const int s0 = m0 & 1023;

  if (seg < 2) {
    bf16* dst = seg ? kp : qp;
    const float sc = seg ? 1.f : (0.17677669529663687f * 1.4426950408889634f);
    #pragma unroll
    for (int nt = 0; nt < 2; ++nt) {
      const int n  = n0 + wn + nt*16 + l15;
      const int nn = n & 255;
      const int h = nn >> 5, d = nn & 31;
      const float bvs = bias[n];
      bf16* hb = dst + (((size_t)b*H_ + h)*S_)*DH_ + d;
      #pragma unroll
      for (int mt = 0; mt < 4; ++mt) {
        const int ml = wm + mt*16 + quad*4;
        #pragma unroll
        for (int r = 0; r < 4; ++r)
          hb[(size_t)(s0 + ml + r)*DH_] = (bf16)((acc[mt][nt][r] + bvs) * sc);
      }
    }
  } else {
    #pragma unroll
    for (int nt = 0; nt < 2; ++nt) {
      const int nl = wn + nt*16 + l15;
      const float bvs = bias[n0 + nl];
      #pragma unroll
      for (int mt = 0; mt < 4; ++mt) {
        const int ml = wm + mt*16 + quad*4;
        #pragma unroll
        for (int r = 0; r < 4; ++r)
          Vs[nl][ml + r] = (bf16)(acc[mt][nt][r] + bvs);
      }
    }
    __syncthreads();
    #pragma unroll
    for (int t = 0; t < 2; ++t) {
      const int vrow = (tid >> 3) + 32*t;
      const int soff = (tid & 7) * 16;
      const int nn = (n0 + vrow) & 255;
      const int h = nn >> 5, d = nn & 31;
      bf16* dst = vt + (((size_t)b*H_ + h)*DH_ + d)*S_ + s0 + soff;
      *(bf16x8*)dst       = *(const bf16x8*)&Vs[vrow][soff];
      *(bf16x8*)(dst + 8) = *(const bf16x8*)&Vs[vrow][soff + 8];
    }
  }
}

// ---------------------------------------------------------------------------
// Generic GEMM 128x64 tile, BK=64 — used for FF1.  K multiple of 64.
// ---------------------------------------------------------------------------
template<bool RELU, bool OUT_BF16>
__global__ __launch_bounds__(256) void gemm_bt(
    const bf16* __restrict__ A, const bf16* __restrict__ BT,
    const float* __restrict__ bias, void* __restrict__ C,
    int M, int N, int K)
{
  __shared__ bf16 As[128*64];
  __shared__ bf16 Bs[64*64];
  const int tid  = threadIdx.x;
  const int lane = tid & 63, wave = tid >> 6;
  const int quad = lane >> 4, l15 = lane & 15;
  const int m0 = blockIdx.x * 128;
  const int n0 = blockIdx.y * 64;
  const int wm = (wave & 1) * 64;
  const int wn = (wave >> 1) * 32;

  const bf16* a0 = A  + (size_t)m0 * K;
  const bf16* b0 = BT + (size_t)n0 * K;
  const int row32 = tid >> 3;
  const int gch   = GCH64(tid);
  const int l7    = l15 & 7;

  f32x4 acc[4][2] = {};

  for (int k0 = 0; k0 < K; k0 += 64) {
    __syncthreads();
    #pragma unroll
    for (int i = 0; i < 4; ++i)
      load_lds16(a0 + (size_t)(32*i + row32)*K + k0 + gch,
                 (char*)As + i*4096 + (size_t)wave*1024);
    #pragma unroll
    for (int i = 0; i < 2; ++i)
      load_lds16(b0 + (size_t)(32*i + row32)*K + k0 + gch,
                 (char*)Bs + i*4096 + (size_t)wave*1024);
    __syncthreads();
    #pragma unroll
    for (int kh = 0; kh < 2; ++kh) {
      const int fq = (((kh*4 + quad) ^ l7)) * 8;
      bf16x8 af[4], bfr[2];
      #pragma unroll
      for (int mt = 0; mt < 4; ++mt)
        af[mt] = *(const bf16x8*)(As + (wm + mt*16 + l15)*64 + fq);
      #pragma unroll
      for (int nt = 0; nt < 2; ++nt)
        bfr[nt] = *(const bf16x8*)(Bs + (wn + nt*16 + l15)*64 + fq);
      #pragma unroll
      for (int mt = 0; mt < 4; ++mt)
        #pragma unroll
        for (int nt = 0; nt < 2; ++nt)
          acc[mt][nt] = __builtin_amdgcn_mfma_f32_16x16x32_bf16(af[mt], bfr[nt], acc[mt][nt], 0, 0, 0);
    }
  }

  #pragma unroll
  for (int nt = 0; nt < 2; ++nt) {
    const int n = n0 + wn + nt*16 + l15;
    const float bvs = bias[n];
    #pragma unroll
    for (int mt = 0; mt < 4; ++mt) {
      const int mr = m0 + wm + mt*16 + quad*4;
      #pragma unroll
      for (int r = 0; r < 4; ++r) {
        float v = acc[mt][nt][r] + bvs;
        if (RELU) v = fmaxf(v, 0.f);
        if (OUT_BF16) ((bf16*)C)[(size_t)(mr + r)*N + n] = (bf16)v;
        else          ((float*)C)[(size_t)(mr + r)*N + n] = v;
      }
    }
  }
}

// ---------------------------------------------------------------------------
// GEMM 64x64 tile, BK=32 — classifier only (NMASK).
// ---------------------------------------------------------------------------
template<bool RELU, bool OUT_BF16, bool NMASK>
__global__ __launch_bounds__(256) void gemm_bt64(
    const bf16* __restrict__ A, const bf16* __restrict__ BT,
    const float* __restrict__ bias, void* __restrict__ C,
    int M, int N, int K)
{
  __shared__ bf16 As[64*32];
  __shared__ bf16 Bs[64*32];
  const int tid  = threadIdx.x;
  const int lane = tid & 63, wave = tid >> 6;
  const int quad = lane >> 4, l15 = lane & 15;
  const int m0 = blockIdx.x * 64;
  const int n0 = blockIdx.y * 64;
  const int wm = (wave & 1) * 32;
  const int wn = (wave >> 1) * 32;

  const bf16* a0 = A  + (size_t)m0 * K;
  const bf16* b0 = BT + (size_t)n0 * K;
  const int row = tid >> 2;
  const int chs = SRC_CHS(tid);
  const int q8  = FRAG_Q8(quad, l15);

  f32x4 acc[2][2] = {};

  for (int k0 = 0; k0 < K; k0 += 32) {
    __syncthreads();
    load_lds16(a0 + (size_t)row*K + k0 + chs, (char*)As + (size_t)wave*1024);
    load_lds16(b0 + (size_t)row*K + k0 + chs, (char*)Bs + (size_t)wave*1024);
    __syncthreads();
    bf16x8 af[2], bfr[2];
    #pragma unroll
    for (int mt = 0; mt < 2; ++mt)
      af[mt] = *(const bf16x8*)(As + (wm + mt*16 + l15)*32 + q8);
    #pragma unroll
    for (int nt = 0; nt < 2; ++nt)
      bfr[nt] = *(const bf16x8*)(Bs + (wn + nt*16 + l15)*32 + q8);
    #pragma unroll
    for (int mt = 0; mt < 2; ++mt)
      #pragma unroll
      for (int nt = 0; nt < 2; ++nt)
        acc[mt][nt] = __builtin_amdgcn_mfma_f32_16x16x32_bf16(af[mt], bfr[nt], acc[mt][nt], 0, 0, 0);
  }

  #pragma unroll
  for (int nt = 0; nt < 2; ++nt) {
    const int n = n0 + wn + nt*16 + l15;
    if (NMASK && n >= N) continue;
    const float bvs = bias[n];
    #pragma unroll
    for (int mt = 0; mt < 2; ++mt) {
      const int mr = m0 + wm + mt*16 + quad*4;
      #pragma unroll
      for (int r = 0; r < 4; ++r) {
        float v = acc[mt][nt][r] + bvs;
        if (RELU) v = fmaxf(v, 0.f);
        if (OUT_BF16) ((bf16*)C)[(size_t)(mr + r)*N + n] = (bf16)v;
        else          ((float*)C)[(size_t)(mr + r)*N + n] = v;
      }
    }
  }
}

// ---------------------------------------------------------------------------
// Fused GEMM + residual + LayerNorm, BK=64:  x = LN(x + A@BT^T + b)*g + be.
// M-tile 16, N=256, grid (M/16)=512.  LDS: 2K + 32K + 8.25K + 0.5K = 43K.
// ---------------------------------------------------------------------------
__global__ __launch_bounds__(256) void gemm_ln(
    const bf16* __restrict__ A, const bf16* __restrict__ BT,
    const float* __restrict__ bias, const float* __restrict__ g,
    const float* __restrict__ be, bf16* xio, int K)
{
  __shared__ bf16 As[16*64];        // 2 KB
  __shared__ bf16 Bs[256*64];       // 32 KB
  __shared__ bf16 Xs[16][264];      // 8.25 KB
  __shared__ float sums[4][16][2];

  const int tid  = threadIdx.x;
  const int lane = tid & 63, wave = tid >> 6;
  const int quad = lane >> 4, l15 = lane & 15;
  const int m0 = blockIdx.x * 16;
  const int wn = wave * 64;

  const bf16* a0 = A + (size_t)m0 * K;
  const int row32 = tid >> 3;
  const int gch   = GCH64(tid);
  const int l7    = l15 & 7;

  f32x4 acc[4] = {};

  for (int k0 = 0; k0 < K; k0 += 64) {
    __syncthreads();
    if (wave < 2)
      load_lds16(a0 + (size_t)(wave*8 + (lane >> 3))*K + k0 + GCH64(lane),
                 (char*)As + (size_t)wave*1024);
    #pragma unroll
    for (int j = 0; j < 8; ++j)
      load_lds16(BT + (size_t)(32*j + row32)*K + k0 + gch,
                 (char*)Bs + j*4096 + (size_t)wave*1024);
    __syncthreads();
    #pragma unroll
    for (int kh = 0; kh < 2; ++kh) {
      const int fq = (((kh*4 + quad) ^ l7)) * 8;
      const bf16x8 af = *(const bf16x8*)(As + l15*64 + fq);
      #pragma unroll
      for (int nt = 0; nt < 4; ++nt) {
        const bf16x8 bfr = *(const bf16x8*)(Bs + (wn + nt*16 + l15)*64 + fq);
        acc[nt] = __builtin_amdgcn_mfma_f32_16x16x32_bf16(af, bfr, acc[nt], 0, 0, 0);
      }
    }
  }

  {
    const int xr = tid >> 4, xc = (tid & 15) * 16;
    const bf16* src = xio + (size_t)(m0 + xr)*D_ + xc;
    *(bf16x8*)&Xs[xr][xc]     = *(const bf16x8*)src;
    *(bf16x8*)&Xs[xr][xc + 8] = *(const bf16x8*)(src + 8);
  }
  __syncthreads();

  float v[4][4];
  float bvs[4];
  #pragma unroll
  for (int nt = 0; nt < 4; ++nt) bvs[nt] = bias[wn + nt*16 + l15];
  #pragma unroll
  for (int r = 0; r < 4; ++r) {
    const int rr = quad*4 + r;
    float ls = 0.f, lq = 0.f;
    #pragma unroll
    for (int nt = 0; nt < 4; ++nt) {
      const float y = acc[nt][r] + bvs[nt];
      const float xv = b2f(*(const unsigned short*)&Xs[rr][wn + nt*16 + l15]);
      const float vv = xv + y;
      v[r][nt] = vv;
      ls += vv;
      lq += vv*vv;
    }
    ls = red_sum16(ls);
    lq = red_sum16(lq);
    if (l15 == 0) { sums[wave][rr][0] = ls; sums[wave][rr][1] = lq; }
  }
  __syncthreads();

  float gv[4], bev[4];
  #pragma unroll
  for (int nt = 0; nt < 4; ++nt) {
    gv[nt]  = g[wn + nt*16 + l15];
    bev[nt] = be[wn + nt*16 + l15];
  }
  #pragma unroll
  for (int r = 0; r < 4; ++r) {
    const int rr = quad*4 + r;
    const float ts = sums[0][rr][0] + sums[1][rr][0] + sums[2][rr][0] + sums[3][rr][0];
    const float tq = sums[0][rr][1] + sums[1][rr][1] + sums[2][rr][1] + sums[3][rr][1];
    const float mean = ts * (1.f/256.f);
    const float var  = tq * (1.f/256.f) - mean*mean;
    const float inv  = rsqrtf(var + 1e-5f);
    #pragma unroll
    for (int nt = 0; nt < 4; ++nt) {
      const bf16 o = (bf16)((v[r][nt] - mean)*inv*gv[nt] + bev[nt]);
      Xs[rr][wn + nt*16 + l15] = o;
    }
  }
  __syncthreads();

  {
    const int xr = tid >> 4, xc = (tid & 15) * 16;
    bf16* dst = xio + (size_t)(m0 + xr)*D_ + xc;
    *(bf16x8*)dst       = *(const bf16x8*)&Xs[xr][xc];
    *(bf16x8*)(dst + 8) = *(const bf16x8*)&Xs[xr][xc + 8];
  }
}

// ---------------------------------------------------------------------------
// Flash attention, causal — r12/r15 form (best measured).
// ---------------------------------------------------------------------------
#define PSTR 68
__global__ __launch_bounds__(256) void attn_kernel(
    const bf16* __restrict__ qp, const bf16* __restrict__ kp,
    const bf16* __restrict__ vt, const int* __restrict__ tsl,
    bf16* __restrict__ out)
{
  const int h = blockIdx.y, b = blockIdx.z;
  const int lane = threadIdx.x & 63, wave = threadIdx.x >> 6;
  const int quad = lane >> 4, l15 = lane & 15;
  const int sid = blockIdx.x + wave*16;
  const int q0 = sid*16;
  const int len = tsl[b];

  __shared__ bf16 Pl[4][16*PSTR];

  const size_t bh = (size_t)b*H_ + h;
  const bf16* qb = qp + bh*S_*DH_;
  const bf16* kb = kp + bh*S_*DH_;
  const bf16* vb = vt + bh*DH_*S_;

  const bf16x8 qf = *(const bf16x8*)(qb + (size_t)(q0 + l15)*DH_ + quad*8);

  float lacc = 0.f;
  f32x4 o0 = {0.f,0.f,0.f,0.f}, o1 = {0.f,0.f,0.f,0.f};

  bf16* pw = &Pl[wave][0];
  const int qr = q0 + l15;
  const bool full = (len >= S_);
  const int dt = sid >> 2;

  bf16x8 kf[4];
  #pragma unroll
  for (int nt = 0; nt < 4; ++nt)
    kf[nt] = *(const bf16x8*)(kb + (size_t)(nt*16 + l15)*DH_ + quad*8);

  for (int ks = 0; ks <= dt; ++ks) {
    const int k0 = ks*64;
    bf16x8 vf[4];
    #pragma unroll
    for (int kc = 0; kc < 2; ++kc) {
      vf[kc*2]   = *(const bf16x8*)(vb + (size_t)l15*S_      + k0 + kc*32 + quad*8);
      vf[kc*2+1] = *(const bf16x8*)(vb + (size_t)(16+l15)*S_ + k0 + kc*32 + quad*8);
    }
    f32x4 s[4];
    #pragma unroll
    for (int nt = 0; nt < 4; ++nt) {
      const f32x4 z = {0.f,0.f,0.f,0.f};
      s[nt] = __builtin_amdgcn_mfma_f32_16x16x32_bf16(kf[nt], qf, z, 0, 0, 0);
    }
    bf16x8 kn[4];
    if (ks < dt) {
      const int k1 = k0 + 64;
      #pragma unroll
      for (int nt = 0; nt < 4; ++nt)
        kn[nt] = *(const bf16x8*)(kb + (size_t)(k1 + nt*16 + l15)*DH_ + quad*8);
    }
    #pragma unroll
    for (int nt = 0; nt < 4; ++nt) {
      float p0, p1, p2, p3;
      if (full && ks < dt) {
        p0 = exp2f(s[nt][0]);
        p1 = exp2f(s[nt][1]);
        p2 = exp2f(s[nt][2]);
        p3 = exp2f(s[nt][3]);
      } else {
        const int kbase = k0 + nt*16 + quad*4;
        const bool okq = (qr < len);
        p0 = (okq && kbase+0 <= qr && kbase+0 < len) ? exp2f(s[nt][0]) : 0.f;
        p1 = (okq && kbase+1 <= qr && kbase+1 < len) ? exp2f(s[nt][1]) : 0.f;
        p2 = (okq && kbase+2 <= qr && kbase+2 < len) ? exp2f(s[nt][2]) : 0.f;
        p3 = (okq && kbase+3 <= qr && kbase+3 < len) ? exp2f(s[nt][3]) : 0.f;
      }
      lacc += (p0 + p1) + (p2 + p3);
      uint2 w;
      w.x = (unsigned)f2b(p0) | ((unsigned)f2b(p1) << 16);
      w.y = (unsigned)f2b(p2) | ((unsigned)f2b(p3) << 16);
      *(uint2*)((char*)pw + l15*(PSTR*2) + nt*32 + quad*8) = w;
    }
    asm volatile("s_waitcnt lgkmcnt(0)" ::: "memory");
    #pragma unroll
    for (int kc = 0; kc < 2; ++kc) {
      const bf16x8 pf = *(const bf16x8*)(pw + l15*PSTR + kc*32 + quad*8);
      o0 = __builtin_amdgcn_mfma_f32_16x16x32_bf16(pf, vf[kc*2],   o0, 0, 0, 0);
      o1 = __builtin_amdgcn_mfma_f32_16x16x32_bf16(pf, vf[kc*2+1], o1, 0, 0, 0);
    }
    if (ks < dt) {
      #pragma unroll
      for (int nt = 0; nt < 4; ++nt) kf[nt] = kn[nt];
    }
  }

  float lt = lacc;
  lt += __shfl_xor(lt, 16);
  lt += __shfl_xor(lt, 32);

  bf16* ob = out + (size_t)b*S_*D_ + h*DH_;
  #pragma unroll
  for (int r = 0; r < 4; ++r) {
    const float lr = __shfl(lt, (lane & 48) | (quad*4 + r));
    const float inv = 1.f / fmaxf(lr, 1e-30f);
    const size_t rowoff = (size_t)(q0 + quad*4 + r)*D_;
    ob[rowoff + l15]      = (bf16)(o0[r]*inv);
    ob[rowoff + 16 + l15] = (bf16)(o1[r]*inv);
  }
}

// ---------------------------------------------------------------------------
extern "C" void kernel_launch(void* const* d_in, const int* in_sizes, int n_in,
                              void* d_out, int out_size, void* d_ws, size_t ws_size,
                              hipStream_t stream)
{
  const int*   ids = (const int*)d_in[0];
  const int*   tsl = (const int*)d_in[1];
  const float* emb = (const float*)d_in[2];
  const float* Wq  = (const float*)d_in[3];
  const float* bq  = (const float*)d_in[4];
  const float* Wk  = (const float*)d_in[5];
  const float* bk  = (const float*)d_in[6];
  const float* Wv  = (const float*)d_in[7];
  const float* bv  = (const float*)d_in[8];
  const float* Wo  = (const float*)d_in[9];
  const float* bo  = (const float*)d_in[10];
  const float* W1  = (const float*)d_in[11];
  const float* b1  = (const float*)d_in[12];
  const float* W2  = (const float*)d_in[13];
  const float* b2  = (const float*)d_in[14];
  const float* g1  = (const float*)d_in[15];
  const float* be1 = (const float*)d_in[16];
  const float* g2  = (const float*)d_in[17];
  const float* be2 = (const float*)d_in[18];
  const float* Wc  = (const float*)d_in[19];
  const float* bc  = (const float*)d_in[20];

  if (ws_size < (size_t)40*1024*1024) return;

  char* p = (char*)d_ws;
  auto carve = [&](size_t bytes) { void* r = (void*)p; p += (bytes + 255) & ~(size_t)255; return r; };
  bf16*  x     = (bf16*) carve((size_t)M_*D_*2);
  char*  big   = (char*) carve((size_t)M_*DFF_*2);
  char*  pkbuf = (char*) carve((size_t)12*1024*1024);
  bf16*  WqkvT = (bf16*) carve((size_t)L_*768*256*2);
  bf16*  WoT   = (bf16*) carve((size_t)L_*65536*2);
  bf16*  W1T   = (bf16*) carve((size_t)L_*262144*2);
  bf16*  W2T   = (bf16*) carve((size_t)L_*262144*2);
  bf16*  WcT   = (bf16*) carve((size_t)128*256*2);
  float* bqkv  = (float*)carve((size_t)L_*768*4);

  bf16*  aout = (bf16*)big;
  bf16*  ff1  = (bf16*)big;
  bf16*  qp   = (bf16*)pkbuf;
  bf16*  kp   = (bf16*)(pkbuf + (size_t)4*1024*1024);
  bf16*  vt   = (bf16*)(pkbuf + (size_t)8*1024*1024);

  prep_t<<<dim3(32,32,34), dim3(32,8), 0, stream>>>(Wq,Wk,Wv,Wo,W1,W2,Wc,bq,bk,bv,
                                                    ids, emb,
                                                    WqkvT,WoT,W1T,W2T,WcT,bqkv, x);

  for (int l = 0; l < L_; ++l) {
    gemm_qkv<<<dim3(64,12), 256, 0, stream>>>(
        x, WqkvT + (size_t)l*768*256, bqkv + l*768, qp, kp, vt);
    attn_kernel<<<dim3(16,8,8), 256, 0, stream>>>(qp, kp, vt, tsl, aout);
    gemm_ln<<<dim3(512), 256, 0, stream>>>(
        aout, WoT + (size_t)l*65536, bo + l*256, g1 + l*256, be1 + l*256, x, 256);
    gemm_bt<true,true><<<dim3(64,16), 256, 0, stream>>>(
        x, W1T + (size_t)l*262144, b1 + l*1024, ff1, M_, 1024, 256);
    gemm_ln<<<dim3(512), 256, 0, stream>>>(
        ff1, W2T + (size_t)l*262144, b2 + l*256, g2 + l*256, be2 + l*256, x, 1024);
  }

  gemm_bt64<false,false,true><<<dim3(128,2), 256, 0, stream>>>(
      x, WcT, bc, (float*)d_out, M_, V_, 256);
}

// Round 17
// 423.490 us; speedup vs baseline: 1.1783x; 1.0036x over previous
//
#include <hip/hip_runtime.h>
#include <hip/hip_bf16.h>
#include <stdint.h>

#define B_   8
#define S_   1024
#define D_   256
#define H_   8
#define DH_  32
#define L_   4
#define V_   100
#define DFF_ 1024
#define M_   (B_*S_)   // 8192

using bf16 = __hip_bfloat16;
typedef __bf16 bf16x8 __attribute__((ext_vector_type(8)));
typedef float  f32x4  __attribute__((ext_vector_type(4)));

static __device__ __forceinline__ float b2f(unsigned short u) {
  union { unsigned int i; float f; } w; w.i = ((unsigned int)u) << 16; return w.f;
}
static __device__ __forceinline__ unsigned short f2b(float f) {
  bf16 h = (bf16)f; return *(unsigned short*)&h;
}

// async global->LDS DMA: 16B/lane, LDS dest = wave-uniform base + lane*16
static __device__ __forceinline__ void load_lds16(const void* g, void* l) {
  __builtin_amdgcn_global_load_lds((const __attribute__((address_space(1))) void*)g,
                                   (__attribute__((address_space(3))) void*)l,
                                   16, 0, 0);
}

// BK=32 swizzle (classifier only)
#define SRC_CHS(tid)  ((((tid) & 3) ^ (((tid) >> 3) & 3)) * 8)
#define FRAG_Q8(quad, l15)  (((quad) ^ (((l15) >> 1) & 3)) * 8)

// BK=64 swizzle: chunk c of row r stored at physical chunk c ^ (r&7).
#define GCH64(tid)  ((((tid) & 7) ^ (((tid) >> 3) & 7)) * 8)

// DPP cross-lane reductions over the 16-lane l15 group (== DPP row).
template<int CTRL>
static __device__ __forceinline__ float dppf(float v) {
  union { float f; int i; } a, r;
  a.f = v;
  r.i = __builtin_amdgcn_update_dpp(0, a.i, CTRL, 0xF, 0xF, true);
  return r.f;
}
static __device__ __forceinline__ float red_sum16(float v) {
  v += dppf<0xB1>(v);
  v += dppf<0x4E>(v);
  v += dppf<0x141>(v);
  v += dppf<0x140>(v);
  return v;
}

// ---------------------------------------------------------------------------
// Prep: weight transposes (z 0..24), fused qkv bias (z 25), embedding+PE
// (z 26..33).  grid (32,32,34), block (32,8).
// ---------------------------------------------------------------------------
__global__ void prep_t(const float* __restrict__ Wq, const float* __restrict__ Wk,
                       const float* __restrict__ Wv, const float* __restrict__ Wo,
                       const float* __restrict__ W1, const float* __restrict__ W2,
                       const float* __restrict__ Wc,
                       const float* __restrict__ bq, const float* __restrict__ bk,
                       const float* __restrict__ bv,
                       const int* __restrict__ ids, const float* __restrict__ emb,
                       bf16* __restrict__ WqkvT, bf16* __restrict__ WoT,
                       bf16* __restrict__ W1T, bf16* __restrict__ W2T,
                       bf16* __restrict__ WcT, float* __restrict__ bqkv,
                       bf16* __restrict__ x)
{
  const int z = blockIdx.z;
  const int tid = threadIdx.y*32 + threadIdx.x;
  if (z >= 26) {                                 // embedding + sinusoidal PE
    const int bs = (z - 26)*1024 + blockIdx.y*32 + blockIdx.x;
    const int d  = tid;
    const int s  = bs & (S_-1);
    const int id = ids[bs];
    const int f  = (d < 128) ? (2*d) : (2*(d-128)+1);
    const float inv = powf(10000.f, -(float)f * (1.f/256.f));
    const float pe  = sinf((float)s * inv);
    x[(size_t)bs*D_ + d] = (bf16)(emb[(size_t)id*D_ + d] + pe);
    return;
  }
  if (z == 25) {                                 // fused qkv bias
    if (blockIdx.x || blockIdx.y) return;
    for (int i = tid; i < L_*768; i += 256) {
      const int l2 = i / 768, j = i % 768;
      const float* src = (j < 256) ? bq : (j < 512) ? bk : bv;
      bqkv[i] = src[l2*256 + (j & 255)];
    }
    return;
  }
  const float* src; bf16* dst; int R, C, Cd;
  if (z < 12) {
    const int l = z / 3, w = z % 3;
    src = ((w == 0) ? Wq : (w == 1) ? Wk : Wv) + (size_t)l*65536;
    R = 256; C = 256; Cd = 256;
    dst = WqkvT + (size_t)l*196608 + (size_t)w*65536;
  } else if (z < 16) {
    const int l = z - 12;
    src = Wo + (size_t)l*65536; R = 256; C = 256; Cd = 256;
    dst = WoT + (size_t)l*65536;
  } else if (z < 20) {
    const int l = z - 16;
    src = W1 + (size_t)l*262144; R = 256; C = 1024; Cd = 1024;
    dst = W1T + (size_t)l*262144;
  } else if (z < 24) {
    const int l = z - 20;
    src = W2 + (size_t)l*262144; R = 1024; C = 256; Cd = 256;
    dst = W2T + (size_t)l*262144;
  } else {
    src = Wc; R = 256; C = 100; Cd = 128;
    dst = WcT;
  }
  const int c0 = blockIdx.x*32, r0 = blockIdx.y*32;
  if (c0 >= Cd || r0 >= R) return;
  __shared__ float t[32][33];
  #pragma unroll
  for (int i = 0; i < 4; ++i) {
    const int r = r0 + threadIdx.y + i*8;
    const int c = c0 + threadIdx.x;
    t[threadIdx.y + i*8][threadIdx.x] = (r < R && c < C) ? src[(size_t)r*C + c] : 0.f;
  }
  __syncthreads();
  #pragma unroll
  for (int i = 0; i < 4; ++i) {
    const int c = c0 + threadIdx.y + i*8;
    const int r = r0 + threadIdx.x;
    if (c < Cd && r < R)
      dst[(size_t)c*R + r] = (bf16)t[threadIdx.x][threadIdx.y + i*8];
  }
}

// ---------------------------------------------------------------------------
// QKV GEMM, BK=64, packed epilogue -> qp (pre-scaled), kp, vt[bh][d][s].
// ---------------------------------------------------------------------------
__global__ __launch_bounds__(256) void gemm_qkv(
    const bf16* __restrict__ A, const bf16* __restrict__ BT,
    const float* __restrict__ bias,
    bf16* __restrict__ qp, bf16* __restrict__ kp, bf16* __restrict__ vt)
{
  __shared__ bf16 As[128*64];
  __shared__ bf16 Bs[64*64];
  __shared__ bf16 Vs[64][136];
  const int tid  = threadIdx.x;
  const int lane = tid & 63, wave = tid >> 6;
  const int quad = lane >> 4, l15 = lane & 15;
  const int m0 = blockIdx.x * 128;
  const int n0 = blockIdx.y * 64;
  const int wm = (wave & 1) * 64;
  const int wn = (wave >> 1) * 32;
  const int K = 256;

  const bf16* a0 = A  + (size_t)m0 * K;
  const bf16* b0 = BT + (size_t)n0 * K;
  const int row32 = tid >> 3;
  const int gch   = GCH64(tid);
  const int l7    = l15 & 7;

  f32x4 acc[4][2] = {};

  for (int k0 = 0; k0 < K; k0 += 64) {
    __syncthreads();
    #pragma unroll
    for (int i = 0; i < 4; ++i)
      load_lds16(a0 + (size_t)(32*i + row32)*K + k0 + gch,
                 (char*)As + i*4096 + (size_t)wave*1024);
    #pragma unroll
    for (int i = 0; i < 2; ++i)
      load_lds16(b0 + (size_t)(32*i + row32)*K + k0 + gch,
                 (char*)Bs + i*4096 + (size_t)wave*1024);
    __syncthreads();
    #pragma unroll
    for (int kh = 0; kh < 2; ++kh) {
      const int fq = (((kh*4 + quad) ^ l7)) * 8;
      bf16x8 af[4], bfr[2];
      #pragma unroll
      for (int mt = 0; mt < 4; ++mt)
        af[mt] = *(const bf16x8*)(As + (wm + mt*16 + l15)*64 + fq);
      #pragma unroll
      for (int nt = 0; nt < 2; ++nt)
        bfr[nt] = *(const bf16x8*)(Bs + (wn + nt*16 + l15)*64 + fq);
      #pragma unroll
      for (int mt = 0; mt < 4; ++mt)
        #pragma unroll
        for (int nt = 0; nt < 2; ++nt)
          acc[mt][nt] = __builtin_amdgcn_mfma_f32_16x16x32_bf16(af[mt], bfr[nt], acc[mt][nt], 0, 0, 0);
    }
  }

  const int seg = n0 >> 8;            // 0=Q, 1=K, 2=V
  const int b  = m0 >> 10;
  const int s0 = m0 & 1023;

  if (seg < 2) {
    bf16* dst = seg ? kp : qp;
    const float sc = seg ? 1.f : (0.17677669529663687f * 1.4426950408889634f);
    #pragma unroll
    for (int nt = 0; nt < 2; ++nt) {
      const int n  = n0 + wn + nt*16 + l15;
      const int nn = n & 255;
      const int h = nn >> 5, d = nn & 31;
      const float bvs = bias[n];
      bf16* hb = dst + (((size_t)b*H_ + h)*S_)*DH_ + d;
      #pragma unroll
      for (int mt = 0; mt < 4; ++mt) {
        const int ml = wm + mt*16 + quad*4;
        #pragma unroll
        for (int r = 0; r < 4; ++r)
          hb[(size_t)(s0 + ml + r)*DH_] = (bf16)((acc[mt][nt][r] + bvs) * sc);
      }
    }
  } else {
    #pragma unroll
    for (int nt = 0; nt < 2; ++nt) {
      const int nl = wn + nt*16 + l15;
      const float bvs = bias[n0 + nl];
      #pragma unroll
      for (int mt = 0; mt < 4; ++mt) {
        const int ml = wm + mt*16 + quad*4;
        #pragma unroll
        for (int r = 0; r < 4; ++r)
          Vs[nl][ml + r] = (bf16)(acc[mt][nt][r] + bvs);
      }
    }
    __syncthreads();
    #pragma unroll
    for (int t = 0; t < 2; ++t) {
      const int vrow = (tid >> 3) + 32*t;
      const int soff = (tid & 7) * 16;
      const int nn = (n0 + vrow) & 255;
      const int h = nn >> 5, d = nn & 31;
      bf16* dst = vt + (((size_t)b*H_ + h)*DH_ + d)*S_ + s0 + soff;
      *(bf16x8*)dst       = *(const bf16x8*)&Vs[vrow][soff];
      *(bf16x8*)(dst + 8) = *(const bf16x8*)&Vs[vrow][soff + 8];
    }
  }
}

// ---------------------------------------------------------------------------
// Generic GEMM 128x64 tile, BK=64 — used for FF1.  K multiple of 64.
// ---------------------------------------------------------------------------
template<bool RELU, bool OUT_BF16>
__global__ __launch_bounds__(256) void gemm_bt(
    const bf16* __restrict__ A, const bf16* __restrict__ BT,
    const float* __restrict__ bias, void* __restrict__ C,
    int M, int N, int K)
{
  __shared__ bf16 As[128*64];
  __shared__ bf16 Bs[64*64];
  const int tid  = threadIdx.x;
  const int lane = tid & 63, wave = tid >> 6;
  const int quad = lane >> 4, l15 = lane & 15;
  const int m0 = blockIdx.x * 128;
  const int n0 = blockIdx.y * 64;
  const int wm = (wave & 1) * 64;
  const int wn = (wave >> 1) * 32;

  const bf16* a0 = A  + (size_t)m0 * K;
  const bf16* b0 = BT + (size_t)n0 * K;
  const int row32 = tid >> 3;
  const int gch   = GCH64(tid);
  const int l7    = l15 & 7;

  f32x4 acc[4][2] = {};

  for (int k0 = 0; k0 < K; k0 += 64) {
    __syncthreads();
    #pragma unroll
    for (int i = 0; i < 4; ++i)
      load_lds16(a0 + (size_t)(32*i + row32)*K + k0 + gch,
                 (char*)As + i*4096 + (size_t)wave*1024);
    #pragma unroll
    for (int i = 0; i < 2; ++i)
      load_lds16(b0 + (size_t)(32*i + row32)*K + k0 + gch,
                 (char*)Bs + i*4096 + (size_t)wave*1024);
    __syncthreads();
    #pragma unroll
    for (int kh = 0; kh < 2; ++kh) {
      const int fq = (((kh*4 + quad) ^ l7)) * 8;
      bf16x8 af[4], bfr[2];
      #pragma unroll
      for (int mt = 0; mt < 4; ++mt)
        af[mt] = *(const bf16x8*)(As + (wm + mt*16 + l15)*64 + fq);
      #pragma unroll
      for (int nt = 0; nt < 2; ++nt)
        bfr[nt] = *(const bf16x8*)(Bs + (wn + nt*16 + l15)*64 + fq);
      #pragma unroll
      for (int mt = 0; mt < 4; ++mt)
        #pragma unroll
        for (int nt = 0; nt < 2; ++nt)
          acc[mt][nt] = __builtin_amdgcn_mfma_f32_16x16x32_bf16(af[mt], bfr[nt], acc[mt][nt], 0, 0, 0);
    }
  }

  #pragma unroll
  for (int nt = 0; nt < 2; ++nt) {
    const int n = n0 + wn + nt*16 + l15;
    const float bvs = bias[n];
    #pragma unroll
    for (int mt = 0; mt < 4; ++mt) {
      const int mr = m0 + wm + mt*16 + quad*4;
      #pragma unroll
      for (int r = 0; r < 4; ++r) {
        float v = acc[mt][nt][r] + bvs;
        if (RELU) v = fmaxf(v, 0.f);
        if (OUT_BF16) ((bf16*)C)[(size_t)(mr + r)*N + n] = (bf16)v;
        else          ((float*)C)[(size_t)(mr + r)*N + n] = v;
      }
    }
  }
}

// ---------------------------------------------------------------------------
// GEMM 64x64 tile, BK=32 — classifier only (NMASK).
// ---------------------------------------------------------------------------
template<bool RELU, bool OUT_BF16, bool NMASK>
__global__ __launch_bounds__(256) void gemm_bt64(
    const bf16* __restrict__ A, const bf16* __restrict__ BT,
    const float* __restrict__ bias, void* __restrict__ C,
    int M, int N, int K)
{
  __shared__ bf16 As[64*32];
  __shared__ bf16 Bs[64*32];
  const int tid  = threadIdx.x;
  const int lane = tid & 63, wave = tid >> 6;
  const int quad = lane >> 4, l15 = lane & 15;
  const int m0 = blockIdx.x * 64;
  const int n0 = blockIdx.y * 64;
  const int wm = (wave & 1) * 32;
  const int wn = (wave >> 1) * 32;

  const bf16* a0 = A  + (size_t)m0 * K;
  const bf16* b0 = BT + (size_t)n0 * K;
  const int row = tid >> 2;
  const int chs = SRC_CHS(tid);
  const int q8  = FRAG_Q8(quad, l15);

  f32x4 acc[2][2] = {};

  for (int k0 = 0; k0 < K; k0 += 32) {
    __syncthreads();
    load_lds16(a0 + (size_t)row*K + k0 + chs, (char*)As + (size_t)wave*1024);
    load_lds16(b0 + (size_t)row*K + k0 + chs, (char*)Bs + (size_t)wave*1024);
    __syncthreads();
    bf16x8 af[2], bfr[2];
    #pragma unroll
    for (int mt = 0; mt < 2; ++mt)
      af[mt] = *(const bf16x8*)(As + (wm + mt*16 + l15)*32 + q8);
    #pragma unroll
    for (int nt = 0; nt < 2; ++nt)
      bfr[nt] = *(const bf16x8*)(Bs + (wn + nt*16 + l15)*32 + q8);
    #pragma unroll
    for (int mt = 0; mt < 2; ++mt)
      #pragma unroll
      for (int nt = 0; nt < 2; ++nt)
        acc[mt][nt] = __builtin_amdgcn_mfma_f32_16x16x32_bf16(af[mt], bfr[nt], acc[mt][nt], 0, 0, 0);
  }

  #pragma unroll
  for (int nt = 0; nt < 2; ++nt) {
    const int n = n0 + wn + nt*16 + l15;
    if (NMASK && n >= N) continue;
    const float bvs = bias[n];
    #pragma unroll
    for (int mt = 0; mt < 2; ++mt) {
      const int mr = m0 + wm + mt*16 + quad*4;
      #pragma unroll
      for (int r = 0; r < 4; ++r) {
        float v = acc[mt][nt][r] + bvs;
        if (RELU) v = fmaxf(v, 0.f);
        if (OUT_BF16) ((bf16*)C)[(size_t)(mr + r)*N + n] = (bf16)v;
        else          ((float*)C)[(size_t)(mr + r)*N + n] = v;
      }
    }
  }
}

// ---------------------------------------------------------------------------
// Fused GEMM + residual + LayerNorm, BK=64:  x = LN(x + A@BT^T + b)*g + be.
// M-tile 16, N=256, grid (M/16)=512.
// ---------------------------------------------------------------------------
__global__ __launch_bounds__(256) void gemm_ln(
    const bf16* __restrict__ A, const bf16* __restrict__ BT,
    const float* __restrict__ bias, const float* __restrict__ g,
    const float* __restrict__ be, bf16* xio, int K)
{
  __shared__ bf16 As[16*64];
  __shared__ bf16 Bs[256*64];
  __shared__ bf16 Xs[16][264];
  __shared__ float sums[4][16][2];

  const int tid  = threadIdx.x;
  const int lane = tid & 63, wave = tid >> 6;
  const int quad = lane >> 4, l15 = lane & 15;
  const int m0 = blockIdx.x * 16;
  const int wn = wave * 64;

  const bf16* a0 = A + (size_t)m0 * K;
  const int row32 = tid >> 3;
  const int gch   = GCH64(tid);
  const int l7    = l15 & 7;

  f32x4 acc[4] = {};

  for (int k0 = 0; k0 < K; k0 += 64) {
    __syncthreads();
    if (wave < 2)
      load_lds16(a0 + (size_t)(wave*8 + (lane >> 3))*K + k0 + GCH64(lane),
                 (char*)As + (size_t)wave*1024);
    #pragma unroll
    for (int j = 0; j < 8; ++j)
      load_lds16(BT + (size_t)(32*j + row32)*K + k0 + gch,
                 (char*)Bs + j*4096 + (size_t)wave*1024);
    __syncthreads();
    #pragma unroll
    for (int kh = 0; kh < 2; ++kh) {
      const int fq = (((kh*4 + quad) ^ l7)) * 8;
      const bf16x8 af = *(const bf16x8*)(As + l15*64 + fq);
      #pragma unroll
      for (int nt = 0; nt < 4; ++nt) {
        const bf16x8 bfr = *(const bf16x8*)(Bs + (wn + nt*16 + l15)*64 + fq);
        acc[nt] = __builtin_amdgcn_mfma_f32_16x16x32_bf16(af, bfr, acc[nt], 0, 0, 0);
      }
    }
  }

  {
    const int xr = tid >> 4, xc = (tid & 15) * 16;
    const bf16* src = xio + (size_t)(m0 + xr)*D_ + xc;
    *(bf16x8*)&Xs[xr][xc]     = *(const bf16x8*)src;
    *(bf16x8*)&Xs[xr][xc + 8] = *(const bf16x8*)(src + 8);
  }
  __syncthreads();

  float v[4][4];
  float bvs[4];
  #pragma unroll
  for (int nt = 0; nt < 4; ++nt) bvs[nt] = bias[wn + nt*16 + l15];
  #pragma unroll
  for (int r = 0; r < 4; ++r) {
    const int rr = quad*4 + r;
    float ls = 0.f, lq = 0.f;
    #pragma unroll
    for (int nt = 0; nt < 4; ++nt) {
      const float y = acc[nt][r] + bvs[nt];
      const float xv = b2f(*(const unsigned short*)&Xs[rr][wn + nt*16 + l15]);
      const float vv = xv + y;
      v[r][nt] = vv;
      ls += vv;
      lq += vv*vv;
    }
    ls = red_sum16(ls);
    lq = red_sum16(lq);
    if (l15 == 0) { sums[wave][rr][0] = ls; sums[wave][rr][1] = lq; }
  }
  __syncthreads();

  float gv[4], bev[4];
  #pragma unroll
  for (int nt = 0; nt < 4; ++nt) {
    gv[nt]  = g[wn + nt*16 + l15];
    bev[nt] = be[wn + nt*16 + l15];
  }
  #pragma unroll
  for (int r = 0; r < 4; ++r) {
    const int rr = quad*4 + r;
    const float ts = sums[0][rr][0] + sums[1][rr][0] + sums[2][rr][0] + sums[3][rr][0];
    const float tq = sums[0][rr][1] + sums[1][rr][1] + sums[2][rr][1] + sums[3][rr][1];
    const float mean = ts * (1.f/256.f);
    const float var  = tq * (1.f/256.f) - mean*mean;
    const float inv  = rsqrtf(var + 1e-5f);
    #pragma unroll
    for (int nt = 0; nt < 4; ++nt) {
      const bf16 o = (bf16)((v[r][nt] - mean)*inv*gv[nt] + bev[nt]);
      Xs[rr][wn + nt*16 + l15] = o;
    }
  }
  __syncthreads();

  {
    const int xr = tid >> 4, xc = (tid & 15) * 16;
    bf16* dst = xio + (size_t)(m0 + xr)*D_ + xc;
    *(bf16x8*)dst       = *(const bf16x8*)&Xs[xr][xc];
    *(bf16x8*)(dst + 8) = *(const bf16x8*)&Xs[xr][xc + 8];
  }
}

// ---------------------------------------------------------------------------
// Flash attention, causal — SOFTWARE-PIPELINED P roundtrip.
// Double P buffer per wave; iteration ks: (1) issue ds_read of P(ks)
// (written LAST iteration — its waitcnt drains long-retired ops), (2) compute
// QK/exp/pack/ds_write for tile ks+1 (independent of the read), (3) PV(ks).
// The ~120cyc LDS read latency hides under phase (2).  No asm barrier — the
// compiler's precise lgkmcnt tracking handles the dependencies.
// Max-free exp2 softmax (Q pre-scaled), transposed score MFMA.
// ---------------------------------------------------------------------------
#define PSTR 68
__global__ __launch_bounds__(256) void attn_kernel(
    const bf16* __restrict__ qp, const bf16* __restrict__ kp,
    const bf16* __restrict__ vt, const int* __restrict__ tsl,
    bf16* __restrict__ out)
{
  const int h = blockIdx.y, b = blockIdx.z;
  const int lane = threadIdx.x & 63, wave = threadIdx.x >> 6;
  const int quad = lane >> 4, l15 = lane & 15;
  const int sid = blockIdx.x + wave*16;
  const int q0 = sid*16;
  const int len = tsl[b];

  __shared__ bf16 Pl[4][2][16*PSTR];   // double-buffered P per wave

  const size_t bh = (size_t)b*H_ + h;
  const bf16* qb = qp + bh*S_*DH_;
  const bf16* kb = kp + bh*S_*DH_;
  const bf16* vb = vt + bh*DH_*S_;

  const bf16x8 qf = *(const bf16x8*)(qb + (size_t)(q0 + l15)*DH_ + quad*8);

  float lacc = 0.f;
  f32x4 o0 = {0.f,0.f,0.f,0.f}, o1 = {0.f,0.f,0.f,0.f};

  const int qr = q0 + l15;
  const bool full = (len >= S_);
  const int dt = sid >> 2;

  // compute p(tile t) from kf into buf[t&1]
  auto make_p = [&](int t, const bf16x8* kfr) {
    bf16* pw = &Pl[wave][t & 1][0];
    f32x4 s[4];
    #pragma unroll
    for (int nt = 0; nt < 4; ++nt) {
      const f32x4 z = {0.f,0.f,0.f,0.f};
      s[nt] = __builtin_amdgcn_mfma_f32_16x16x32_bf16(kfr[nt], qf, z, 0, 0, 0);
    }
    const int k0 = t*64;
    #pragma unroll
    for (int nt = 0; nt < 4; ++nt) {
      float p0, p1, p2, p3;
      if (full && t < dt) {
        p0 = exp2f(s[nt][0]);
        p1 = exp2f(s[nt][1]);
        p2 = exp2f(s[nt][2]);
        p3 = exp2f(s[nt][3]);
      } else {
        const int kbase = k0 + nt*16 + quad*4;
        const bool okq = (qr < len);
        p0 = (okq && kbase+0 <= qr && kbase+0 < len) ? exp2f(s[nt][0]) : 0.f;
        p1 = (okq && kbase+1 <= qr && kbase+1 < len) ? exp2f(s[nt][1]) : 0.f;
        p2 = (okq && kbase+2 <= qr && kbase+2 < len) ? exp2f(s[nt][2]) : 0.f;
        p3 = (okq && kbase+3 <= qr && kbase+3 < len) ? exp2f(s[nt][3]) : 0.f;
      }
      lacc += (p0 + p1) + (p2 + p3);
      uint2 w;
      w.x = (unsigned)f2b(p0) | ((unsigned)f2b(p1) << 16);
      w.y = (unsigned)f2b(p2) | ((unsigned)f2b(p3) << 16);
      *(uint2*)((char*)pw + l15*(PSTR*2) + nt*32 + quad*8) = w;
    }
  };

  // prologue: K(0), V(0); p(0) -> buf0; then kf <- K(1)
  bf16x8 kf[4], vf[4];
  #pragma unroll
  for (int nt = 0; nt < 4; ++nt)
    kf[nt] = *(const bf16x8*)(kb + (size_t)(nt*16 + l15)*DH_ + quad*8);
  #pragma unroll
  for (int kc = 0; kc < 2; ++kc) {
    vf[kc*2]   = *(const bf16x8*)(vb + (size_t)l15*S_      + kc*32 + quad*8);
    vf[kc*2+1] = *(const bf16x8*)(vb + (size_t)(16+l15)*S_ + kc*32 + quad*8);
  }
  make_p(0, kf);
  if (dt > 0) {
    #pragma unroll
    for (int nt = 0; nt < 4; ++nt)
      kf[nt] = *(const bf16x8*)(kb + (size_t)(64 + nt*16 + l15)*DH_ + quad*8);
  }

  for (int ks = 0; ks <= dt; ++ks) {
    // (1) P(ks) read — written last iteration (or prologue): latency hides
    // under phase (2).
    const bf16* rb = &Pl[wave][ks & 1][0];
    bf16x8 pf[2];
    pf[0] = *(const bf16x8*)(rb + l15*PSTR + quad*8);
    pf[1] = *(const bf16x8*)(rb + l15*PSTR + 32 + quad*8);

    // (2) produce P(ks+1) (independent of pf)
    if (ks < dt) {
      make_p(ks + 1, kf);
      if (ks + 1 < dt) {            // reload kf for tile ks+2
        const int k2 = (ks + 2)*64;
        #pragma unroll
        for (int nt = 0; nt < 4; ++nt)
          kf[nt] = *(const bf16x8*)(kb + (size_t)(k2 + nt*16 + l15)*DH_ + quad*8);
      }
    }

    // (3) PV(ks)
    o0 = __builtin_amdgcn_mfma_f32_16x16x32_bf16(pf[0], vf[0], o0, 0, 0, 0);
    o1 = __builtin_amdgcn_mfma_f32_16x16x32_bf16(pf[0], vf[1], o1, 0, 0, 0);
    o0 = __builtin_amdgcn_mfma_f32_16x16x32_bf16(pf[1], vf[2], o0, 0, 0, 0);
    o1 = __builtin_amdgcn_mfma_f32_16x16x32_bf16(pf[1], vf[3], o1, 0, 0, 0);

    // reload vf for tile ks+1
    if (ks < dt) {
      const int k1 = (ks + 1)*64;
      #pragma unroll
      for (int kc = 0; kc < 2; ++kc) {
        vf[kc*2]   = *(const bf16x8*)(vb + (size_t)l15*S_      + k1 + kc*32 + quad*8);
        vf[kc*2+1] = *(const bf16x8*)(vb + (size_t)(16+l15)*S_ + k1 + kc*32 + quad*8);
      }
    }
  }

  float lt = lacc;
  lt += __shfl_xor(lt, 16);
  lt += __shfl_xor(lt, 32);

  bf16* ob = out + (size_t)b*S_*D_ + h*DH_;
  #pragma unroll
  for (int r = 0; r < 4; ++r) {
    const float lr = __shfl(lt, (lane & 48) | (quad*4 + r));
    const float inv = 1.f / fmaxf(lr, 1e-30f);
    const size_t rowoff = (size_t)(q0 + quad*4 + r)*D_;
    ob[rowoff + l15]      = (bf16)(o0[r]*inv);
    ob[rowoff + 16 + l15] = (bf16)(o1[r]*inv);
  }
}

// ---------------------------------------------------------------------------
extern "C" void kernel_launch(void* const* d_in, const int* in_sizes, int n_in,
                              void* d_out, int out_size, void* d_ws, size_t ws_size,
                              hipStream_t stream)
{
  const int*   ids = (const int*)d_in[0];
  const int*   tsl = (const int*)d_in[1];
  const float* emb = (const float*)d_in[2];
  const float* Wq  = (const float*)d_in[3];
  const float* bq  = (const float*)d_in[4];
  const float* Wk  = (const float*)d_in[5];
  const float* bk  = (const float*)d_in[6];
  const float* Wv  = (const float*)d_in[7];
  const float* bv  = (const float*)d_in[8];
  const float* Wo  = (const float*)d_in[9];
  const float* bo  = (const float*)d_in[10];
  const float* W1  = (const float*)d_in[11];
  const float* b1  = (const float*)d_in[12];
  const float* W2  = (const float*)d_in[13];
  const float* b2  = (const float*)d_in[14];
  const float* g1  = (const float*)d_in[15];
  const float* be1 = (const float*)d_in[16];
  const float* g2  = (const float*)d_in[17];
  const float* be2 = (const float*)d_in[18];
  const float* Wc  = (const float*)d_in[19];
  const float* bc  = (const float*)d_in[20];

  if (ws_size < (size_t)40*1024*1024) return;

  char* p = (char*)d_ws;
  auto carve = [&](size_t bytes) { void* r = (void*)p; p += (bytes + 255) & ~(size_t)255; return r; };
  bf16*  x     = (bf16*) carve((size_t)M_*D_*2);
  char*  big   = (char*) carve((size_t)M_*DFF_*2);
  char*  pkbuf = (char*) carve((size_t)12*1024*1024);
  bf16*  WqkvT = (bf16*) carve((size_t)L_*768*256*2);
  bf16*  WoT   = (bf16*) carve((size_t)L_*65536*2);
  bf16*  W1T   = (bf16*) carve((size_t)L_*262144*2);
  bf16*  W2T   = (bf16*) carve((size_t)L_*262144*2);
  bf16*  WcT   = (bf16*) carve((size_t)128*256*2);
  float* bqkv  = (float*)carve((size_t)L_*768*4);

  bf16*  aout = (bf16*)big;
  bf16*  ff1  = (bf16*)big;
  bf16*  qp   = (bf16*)pkbuf;
  bf16*  kp   = (bf16*)(pkbuf + (size_t)4*1024*1024);
  bf16*  vt   = (bf16*)(pkbuf + (size_t)8*1024*1024);

  prep_t<<<dim3(32,32,34), dim3(32,8), 0, stream>>>(Wq,Wk,Wv,Wo,W1,W2,Wc,bq,bk,bv,
                                                    ids, emb,
                                                    WqkvT,WoT,W1T,W2T,WcT,bqkv, x);

  for (int l = 0; l < L_; ++l) {
    gemm_qkv<<<dim3(64,12), 256, 0, stream>>>(
        x, WqkvT + (size_t)l*768*256, bqkv + l*768, qp, kp, vt);
    attn_kernel<<<dim3(16,8,8), 256, 0, stream>>>(qp, kp, vt, tsl, aout);
    gemm_ln<<<dim3(512), 256, 0, stream>>>(
        aout, WoT + (size_t)l*65536, bo + l*256, g1 + l*256, be1 + l*256, x, 256);
    gemm_bt<true,true><<<dim3(64,16), 256, 0, stream>>>(
        x, W1T + (size_t)l*262144, b1 + l*1024, ff1, M_, 1024, 256);
    gemm_ln<<<dim3(512), 256, 0, stream>>>(
        ff1, W2T + (size_t)l*262144, b2 + l*256, g2 + l*256, be2 + l*256, x, 1024);
  }

  gemm_bt64<false,false,true><<<dim3(128,2), 256, 0, stream>>>(
      x, WcT, bc, (float*)d_out, M_, V_, 256);
}

// Round 18
// 415.651 us; speedup vs baseline: 1.2006x; 1.0189x over previous
//
#include <hip/hip_runtime.h>
#include <hip/hip_bf16.h>
#include <stdint.h>

#define B_   8
#define S_   1024
#define D_   256
#define H_   8
#define DH_  32
#define L_   4
#define V_   100
#define DFF_ 1024
#define M_   (B_*S_)   // 8192

using bf16 = __hip_bfloat16;
typedef __bf16 bf16x8 __attribute__((ext_vector_type(8)));
typedef float  f32x4  __attribute__((ext_vector_type(4)));

static __device__ __forceinline__ float b2f(unsigned short u) {
  union { unsigned int i; float f; } w; w.i = ((unsigned int)u) << 16; return w.f;
}
static __device__ __forceinline__ unsigned short f2b(float f) {
  bf16 h = (bf16)f; return *(unsigned short*)&h;
}

// async global->LDS DMA: 16B/lane, LDS dest = wave-uniform base + lane*16
static __device__ __forceinline__ void load_lds16(const void* g, void* l) {
  __builtin_amdgcn_global_load_lds((const __attribute__((address_space(1))) void*)g,
                                   (__attribute__((address_space(3))) void*)l,
                                   16, 0, 0);
}

// BK=64 swizzle: chunk c (8 of them) of row r stored at phys chunk c^(r&7).
#define GCH64(tid)  ((((tid) & 7) ^ (((tid) >> 3) & 7)) * 8)
// BK=128 swizzle: 16 chunks/row, phys = c ^ (r&15).
#define GCH128(tid) ((((tid) & 15) ^ (((tid) >> 4) & 15)) * 8)

// DPP cross-lane reductions over the 16-lane l15 group (== DPP row).
template<int CTRL>
static __device__ __forceinline__ float dppf(float v) {
  union { float f; int i; } a, r;
  a.f = v;
  r.i = __builtin_amdgcn_update_dpp(0, a.i, CTRL, 0xF, 0xF, true);
  return r.f;
}
static __device__ __forceinline__ float red_sum16(float v) {
  v += dppf<0xB1>(v);
  v += dppf<0x4E>(v);
  v += dppf<0x141>(v);
  v += dppf<0x140>(v);
  return v;
}

// ---------------------------------------------------------------------------
// Prep: weight transposes (z 0..24), fused qkv bias (z 25), embedding+PE
// (z 26..33).  grid (32,32,34), block (32,8).
// ---------------------------------------------------------------------------
__global__ void prep_t(const float* __restrict__ Wq, const float* __restrict__ Wk,
                       const float* __restrict__ Wv, const float* __restrict__ Wo,
                       const float* __restrict__ W1, const float* __restrict__ W2,
                       const float* __restrict__ Wc,
                       const float* __restrict__ bq, const float* __restrict__ bk,
                       const float* __restrict__ bv,
                       const int* __restrict__ ids, const float* __restrict__ emb,
                       bf16* __restrict__ WqkvT, bf16* __restrict__ WoT,
                       bf16* __restrict__ W1T, bf16* __restrict__ W2T,
                       bf16* __restrict__ WcT, float* __restrict__ bqkv,
                       bf16* __restrict__ x)
{
  const int z = blockIdx.z;
  const int tid = threadIdx.y*32 + threadIdx.x;
  if (z >= 26) {                                 // embedding + sinusoidal PE
    const int bs = (z - 26)*1024 + blockIdx.y*32 + blockIdx.x;
    const int d  = tid;
    const int s  = bs & (S_-1);
    const int id = ids[bs];
    const int f  = (d < 128) ? (2*d) : (2*(d-128)+1);
    const float inv = powf(10000.f, -(float)f * (1.f/256.f));
    const float pe  = sinf((float)s * inv);
    x[(size_t)bs*D_ + d] = (bf16)(emb[(size_t)id*D_ + d] + pe);
    return;
  }
  if (z == 25) {                                 // fused qkv bias
    if (blockIdx.x || blockIdx.y) return;
    for (int i = tid; i < L_*768; i += 256) {
      const int l2 = i / 768, j = i % 768;
      const float* src = (j < 256) ? bq : (j < 512) ? bk : bv;
      bqkv[i] = src[l2*256 + (j & 255)];
    }
    return;
  }
  const float* src; bf16* dst; int R, C, Cd;
  if (z < 12) {
    const int l = z / 3, w = z % 3;
    src = ((w == 0) ? Wq : (w == 1) ? Wk : Wv) + (size_t)l*65536;
    R = 256; C = 256; Cd = 256;
    dst = WqkvT + (size_t)l*196608 + (size_t)w*65536;
  } else if (z < 16) {
    const int l = z - 12;
    src = Wo + (size_t)l*65536; R = 256; C = 256; Cd = 256;
    dst = WoT + (size_t)l*65536;
  } else if (z < 20) {
    const int l = z - 16;
    src = W1 + (size_t)l*262144; R = 256; C = 1024; Cd = 1024;
    dst = W1T + (size_t)l*262144;
  } else if (z < 24) {
    const int l = z - 20;
    src = W2 + (size_t)l*262144; R = 1024; C = 256; Cd = 256;
    dst = W2T + (size_t)l*262144;
  } else {
    src = Wc; R = 256; C = 100; Cd = 128;
    dst = WcT;
  }
  const int c0 = blockIdx.x*32, r0 = blockIdx.y*32;
  if (c0 >= Cd || r0 >= R) return;
  __shared__ float t[32][33];
  #pragma unroll
  for (int i = 0; i < 4; ++i) {
    const int r = r0 + threadIdx.y + i*8;
    const int c = c0 + threadIdx.x;
    t[threadIdx.y + i*8][threadIdx.x] = (r < R && c < C) ? src[(size_t)r*C + c] : 0.f;
  }
  __syncthreads();
  #pragma unroll
  for (int i = 0; i < 4; ++i) {
    const int c = c0 + threadIdx.y + i*8;
    const int r = r0 + threadIdx.x;
    if (c < Cd && r < R)
      dst[(size_t)c*R + r] = (bf16)t[threadIdx.x][threadIdx.y + i*8];
  }
}

// ---------------------------------------------------------------------------
// QKV GEMM, BK=64, packed epilogue -> qp (pre-scaled), kp, vt[bh][d][s].
// ---------------------------------------------------------------------------
__global__ __launch_bounds__(256) void gemm_qkv(
    const bf16* __restrict__ A, const bf16* __restrict__ BT,
    const float* __restrict__ bias,
    bf16* __restrict__ qp, bf16* __restrict__ kp, bf16* __restrict__ vt)
{
  __shared__ bf16 As[128*64];
  __shared__ bf16 Bs[64*64];
  __shared__ bf16 Vs[64][136];
  const int tid  = threadIdx.x;
  const int lane = tid & 63, wave = tid >> 6;
  const int quad = lane >> 4, l15 = lane & 15;
  const int m0 = blockIdx.x * 128;
  const int n0 = blockIdx.y * 64;
  const int wm = (wave & 1) * 64;
  const int wn = (wave >> 1) * 32;
  const int K = 256;

  const bf16* a0 = A  + (size_t)m0 * K;
  const bf16* b0 = BT + (size_t)n0 * K;
  const int row32 = tid >> 3;
  const int gch   = GCH64(tid);
  const int l7    = l15 & 7;

  f32x4 acc[4][2] = {};

  for (int k0 = 0; k0 < K; k0 += 64) {
    __syncthreads();
    #pragma unroll
    for (int i = 0; i < 4; ++i)
      load_lds16(a0 + (size_t)(32*i + row32)*K + k0 + gch,
                 (char*)As + i*4096 + (size_t)wave*1024);
    #pragma unroll
    for (int i = 0; i < 2; ++i)
      load_lds16(b0 + (size_t)(32*i + row32)*K + k0 + gch,
                 (char*)Bs + i*4096 + (size_t)wave*1024);
    __syncthreads();
    #pragma unroll
    for (int kh = 0; kh < 2; ++kh) {
      const int fq = (((kh*4 + quad) ^ l7)) * 8;
      bf16x8 af[4], bfr[2];
      #pragma unroll
      for (int mt = 0; mt < 4; ++mt)
        af[mt] = *(const bf16x8*)(As + (wm + mt*16 + l15)*64 + fq);
      #pragma unroll
      for (int nt = 0; nt < 2; ++nt)
        bfr[nt] = *(const bf16x8*)(Bs + (wn + nt*16 + l15)*64 + fq);
      #pragma unroll
      for (int mt = 0; mt < 4; ++mt)
        #pragma unroll
        for (int nt = 0; nt < 2; ++nt)
          acc[mt][nt] = __builtin_amdgcn_mfma_f32_16x16x32_bf16(af[mt], bfr[nt], acc[mt][nt], 0, 0, 0);
    }
  }

  const int seg = n0 >> 8;            // 0=Q, 1=K, 2=V
  const int b  = m0 >> 10;
  const int s0 = m0 & 1023;

  if (seg < 2) {
    bf16* dst = seg ? kp : qp;
    const float sc = seg ? 1.f : (0.17677669529663687f * 1.4426950408889634f);
    #pragma unroll
    for (int nt = 0; nt < 2; ++nt) {
      const int n  = n0 + wn + nt*16 + l15;
      const int nn = n & 255;
      const int h = nn >> 5, d = nn & 31;
      const float bvs = bias[n];
      bf16* hb = dst + (((size_t)b*H_ + h)*S_)*DH_ + d;
      #pragma unroll
      for (int mt = 0; mt < 4; ++mt) {
        const int ml = wm + mt*16 + quad*4;
        #pragma unroll
        for (int r = 0; r < 4; ++r)
          hb[(size_t)(s0 + ml + r)*DH_] = (bf16)((acc[mt][nt][r] + bvs) * sc);
      }
    }
  } else {
    #pragma unroll
    for (int nt = 0; nt < 2; ++nt) {
      const int nl = wn + nt*16 + l15;
      const float bvs = bias[n0 + nl];
      #pragma unroll
      for (int mt = 0; mt < 4; ++mt) {
        const int ml = wm + mt*16 + quad*4;
        #pragma unroll
        for (int r = 0; r < 4; ++r)
          Vs[nl][ml + r] = (bf16)(acc[mt][nt][r] + bvs);
      }
    }
    __syncthreads();
    #pragma unroll
    for (int t = 0; t < 2; ++t) {
      const int vrow = (tid >> 3) + 32*t;
      const int soff = (tid & 7) * 16;
      const int nn = (n0 + vrow) & 255;
      const int h = nn >> 5, d = nn & 31;
      bf16* dst = vt + (((size_t)b*H_ + h)*DH_ + d)*S_ + s0 + soff;
      *(bf16x8*)dst       = *(const bf16x8*)&Vs[vrow][soff];
      *(bf16x8*)(dst + 8) = *(const bf16x8*)&Vs[vrow][soff + 8];
    }
  }
}

// ---------------------------------------------------------------------------
// Generic GEMM 128x64 tile, BK=128 — used for FF1 (K=256 -> 2 K-iters).
// LDS 48 KB; occupancy stays 3 blocks/CU (VGPR-capped).  16-chunk swizzle:
// phys chunk = qc ^ (row&15), 2-way banks.
// ---------------------------------------------------------------------------
template<bool RELU, bool OUT_BF16>
__global__ __launch_bounds__(256) void gemm_bt(
    const bf16* __restrict__ A, const bf16* __restrict__ BT,
    const float* __restrict__ bias, void* __restrict__ C,
    int M, int N, int K)
{
  __shared__ bf16 As[128*128];   // 32 KB
  __shared__ bf16 Bs[64*128];    // 16 KB
  const int tid  = threadIdx.x;
  const int lane = tid & 63, wave = tid >> 6;
  const int quad = lane >> 4, l15 = lane & 15;
  const int m0 = blockIdx.x * 128;
  const int n0 = blockIdx.y * 64;
  const int wm = (wave & 1) * 64;
  const int wn = (wave >> 1) * 32;

  const bf16* a0 = A  + (size_t)m0 * K;
  const bf16* b0 = BT + (size_t)n0 * K;
  const int row16 = tid >> 4;            // 0..15
  const int gch   = GCH128(tid);

  f32x4 acc[4][2] = {};

  for (int k0 = 0; k0 < K; k0 += 128) {
    __syncthreads();
    #pragma unroll
    for (int i = 0; i < 8; ++i)
      load_lds16(a0 + (size_t)(16*i + row16)*K + k0 + gch,
                 (char*)As + i*4096 + (size_t)wave*1024);
    #pragma unroll
    for (int i = 0; i < 4; ++i)
      load_lds16(b0 + (size_t)(16*i + row16)*K + k0 + gch,
                 (char*)Bs + i*4096 + (size_t)wave*1024);
    __syncthreads();
    #pragma unroll
    for (int kh = 0; kh < 4; ++kh) {
      const int fq = ((kh*4 + quad) ^ l15) * 8;
      bf16x8 af[4], bfr[2];
      #pragma unroll
      for (int mt = 0; mt < 4; ++mt)
        af[mt] = *(const bf16x8*)(As + (wm + mt*16 + l15)*128 + fq);
      #pragma unroll
      for (int nt = 0; nt < 2; ++nt)
        bfr[nt] = *(const bf16x8*)(Bs + (wn + nt*16 + l15)*128 + fq);
      #pragma unroll
      for (int mt = 0; mt < 4; ++mt)
        #pragma unroll
        for (int nt = 0; nt < 2; ++nt)
          acc[mt][nt] = __builtin_amdgcn_mfma_f32_16x16x32_bf16(af[mt], bfr[nt], acc[mt][nt], 0, 0, 0);
    }
  }

  #pragma unroll
  for (int nt = 0; nt < 2; ++nt) {
    const int n = n0 + wn + nt*16 + l15;
    const float bvs = bias[n];
    #pragma unroll
    for (int mt = 0; mt < 4; ++mt) {
      const int mr = m0 + wm + mt*16 + quad*4;
      #pragma unroll
      for (int r = 0; r < 4; ++r) {
        float v = acc[mt][nt][r] + bvs;
        if (RELU) v = fmaxf(v, 0.f);
        if (OUT_BF16) ((bf16*)C)[(size_t)(mr + r)*N + n] = (bf16)v;
        else          ((float*)C)[(size_t)(mr + r)*N + n] = v;
      }
    }
  }
}

// ---------------------------------------------------------------------------
// GEMM 64x64 tile, BK=64 — classifier (NMASK).  K multiple of 64.
// ---------------------------------------------------------------------------
template<bool RELU, bool OUT_BF16, bool NMASK>
__global__ __launch_bounds__(256) void gemm_bt64(
    const bf16* __restrict__ A, const bf16* __restrict__ BT,
    const float* __restrict__ bias, void* __restrict__ C,
    int M, int N, int K)
{
  __shared__ bf16 As[64*64];    // 8 KB
  __shared__ bf16 Bs[64*64];    // 8 KB
  const int tid  = threadIdx.x;
  const int lane = tid & 63, wave = tid >> 6;
  const int quad = lane >> 4, l15 = lane & 15;
  const int m0 = blockIdx.x * 64;
  const int n0 = blockIdx.y * 64;
  const int wm = (wave & 1) * 32;
  const int wn = (wave >> 1) * 32;

  const bf16* a0 = A  + (size_t)m0 * K;
  const bf16* b0 = BT + (size_t)n0 * K;
  const int row32 = tid >> 3;
  const int gch   = GCH64(tid);
  const int l7    = l15 & 7;

  f32x4 acc[2][2] = {};

  for (int k0 = 0; k0 < K; k0 += 64) {
    __syncthreads();
    #pragma unroll
    for (int i = 0; i < 2; ++i) {
      load_lds16(a0 + (size_t)(32*i + row32)*K + k0 + gch,
                 (char*)As + i*4096 + (size_t)wave*1024);
      load_lds16(b0 + (size_t)(32*i + row32)*K + k0 + gch,
                 (char*)Bs + i*4096 + (size_t)wave*1024);
    }
    __syncthreads();
    #pragma unroll
    for (int kh = 0; kh < 2; ++kh) {
      const int fq = (((kh*4 + quad) ^ l7)) * 8;
      bf16x8 af[2], bfr[2];
      #pragma unroll
      for (int mt = 0; mt < 2; ++mt)
        af[mt] = *(const bf16x8*)(As + (wm + mt*16 + l15)*64 + fq);
      #pragma unroll
      for (int nt = 0; nt < 2; ++nt)
        bfr[nt] = *(const bf16x8*)(Bs + (wn + nt*16 + l15)*64 + fq);
      #pragma unroll
      for (int mt = 0; mt < 2; ++mt)
        #pragma unroll
        for (int nt = 0; nt < 2; ++nt)
          acc[mt][nt] = __builtin_amdgcn_mfma_f32_16x16x32_bf16(af[mt], bfr[nt], acc[mt][nt], 0, 0, 0);
    }
  }

  #pragma unroll
  for (int nt = 0; nt < 2; ++nt) {
    const int n = n0 + wn + nt*16 + l15;
    if (NMASK && n >= N) continue;
    const float bvs = bias[n];
    #pragma unroll
    for (int mt = 0; mt < 2; ++mt) {
      const int mr = m0 + wm + mt*16 + quad*4;
      #pragma unroll
      for (int r = 0; r < 4; ++r) {
        float v = acc[mt][nt][r] + bvs;
        if (RELU) v = fmaxf(v, 0.f);
        if (OUT_BF16) ((bf16*)C)[(size_t)(mr + r)*N + n] = (bf16)v;
        else          ((float*)C)[(size_t)(mr + r)*N + n] = v;
      }
    }
  }
}

// ---------------------------------------------------------------------------
// Fused GEMM + residual + LayerNorm, BK=64:  x = LN(x + A@BT^T + b)*g + be.
// M-tile 16, N=256, grid (M/16)=512.
// ---------------------------------------------------------------------------
__global__ __launch_bounds__(256) void gemm_ln(
    const bf16* __restrict__ A, const bf16* __restrict__ BT,
    const float* __restrict__ bias, const float* __restrict__ g,
    const float* __restrict__ be, bf16* xio, int K)
{
  __shared__ bf16 As[16*64];
  __shared__ bf16 Bs[256*64];
  __shared__ bf16 Xs[16][264];
  __shared__ float sums[4][16][2];

  const int tid  = threadIdx.x;
  const int lane = tid & 63, wave = tid >> 6;
  const int quad = lane >> 4, l15 = lane & 15;
  const int m0 = blockIdx.x * 16;
  const int wn = wave * 64;

  const bf16* a0 = A + (size_t)m0 * K;
  const int row32 = tid >> 3;
  const int gch   = GCH64(tid);
  const int l7    = l15 & 7;

  f32x4 acc[4] = {};

  for (int k0 = 0; k0 < K; k0 += 64) {
    __syncthreads();
    if (wave < 2)
      load_lds16(a0 + (size_t)(wave*8 + (lane >> 3))*K + k0 + GCH64(lane),
                 (char*)As + (size_t)wave*1024);
    #pragma unroll
    for (int j = 0; j < 8; ++j)
      load_lds16(BT + (size_t)(32*j + row32)*K + k0 + gch,
                 (char*)Bs + j*4096 + (size_t)wave*1024);
    __syncthreads();
    #pragma unroll
    for (int kh = 0; kh < 2; ++kh) {
      const int fq = (((kh*4 + quad) ^ l7)) * 8;
      const bf16x8 af = *(const bf16x8*)(As + l15*64 + fq);
      #pragma unroll
      for (int nt = 0; nt < 4; ++nt) {
        const bf16x8 bfr = *(const bf16x8*)(Bs + (wn + nt*16 + l15)*64 + fq);
        acc[nt] = __builtin_amdgcn_mfma_f32_16x16x32_bf16(af, bfr, acc[nt], 0, 0, 0);
      }
    }
  }

  {
    const int xr = tid >> 4, xc = (tid & 15) * 16;
    const bf16* src = xio + (size_t)(m0 + xr)*D_ + xc;
    *(bf16x8*)&Xs[xr][xc]     = *(const bf16x8*)src;
    *(bf16x8*)&Xs[xr][xc + 8] = *(const bf16x8*)(src + 8);
  }
  __syncthreads();

  float v[4][4];
  float bvs[4];
  #pragma unroll
  for (int nt = 0; nt < 4; ++nt) bvs[nt] = bias[wn + nt*16 + l15];
  #pragma unroll
  for (int r = 0; r < 4; ++r) {
    const int rr = quad*4 + r;
    float ls = 0.f, lq = 0.f;
    #pragma unroll
    for (int nt = 0; nt < 4; ++nt) {
      const float y = acc[nt][r] + bvs[nt];
      const float xv = b2f(*(const unsigned short*)&Xs[rr][wn + nt*16 + l15]);
      const float vv = xv + y;
      v[r][nt] = vv;
      ls += vv;
      lq += vv*vv;
    }
    ls = red_sum16(ls);
    lq = red_sum16(lq);
    if (l15 == 0) { sums[wave][rr][0] = ls; sums[wave][rr][1] = lq; }
  }
  __syncthreads();

  float gv[4], bev[4];
  #pragma unroll
  for (int nt = 0; nt < 4; ++nt) {
    gv[nt]  = g[wn + nt*16 + l15];
    bev[nt] = be[wn + nt*16 + l15];
  }
  #pragma unroll
  for (int r = 0; r < 4; ++r) {
    const int rr = quad*4 + r;
    const float ts = sums[0][rr][0] + sums[1][rr][0] + sums[2][rr][0] + sums[3][rr][0];
    const float tq = sums[0][rr][1] + sums[1][rr][1] + sums[2][rr][1] + sums[3][rr][1];
    const float mean = ts * (1.f/256.f);
    const float var  = tq * (1.f/256.f) - mean*mean;
    const float inv  = rsqrtf(var + 1e-5f);
    #pragma unroll
    for (int nt = 0; nt < 4; ++nt) {
      const bf16 o = (bf16)((v[r][nt] - mean)*inv*gv[nt] + bev[nt]);
      Xs[rr][wn + nt*16 + l15] = o;
    }
  }
  __syncthreads();

  {
    const int xr = tid >> 4, xc = (tid & 15) * 16;
    bf16* dst = xio + (size_t)(m0 + xr)*D_ + xc;
    *(bf16x8*)dst       = *(const bf16x8*)&Xs[xr][xc];
    *(bf16x8*)(dst + 8) = *(const bf16x8*)&Xs[xr][xc + 8];
  }
}

// ---------------------------------------------------------------------------
// Flash attention, causal — pipelined P roundtrip (r17) + PERFECT BLOCK
// BALANCE: sid = ((x + 4*wave)&15) + 16*wave makes every block's total
// k-iteration count exactly 34 (was 28..40 -> 18% tail at 4 blocks/CU).
// ---------------------------------------------------------------------------
#define PSTR 68
__global__ __launch_bounds__(256) void attn_kernel(
    const bf16* __restrict__ qp, const bf16* __restrict__ kp,
    const bf16* __restrict__ vt, const int* __restrict__ tsl,
    bf16* __restrict__ out)
{
  const int h = blockIdx.y, b = blockIdx.z;
  const int lane = threadIdx.x & 63, wave = threadIdx.x >> 6;
  const int quad = lane >> 4, l15 = lane & 15;
  const int sid = ((blockIdx.x + 4*wave) & 15) + 16*wave;   // balanced bijection
  const int q0 = sid*16;
  const int len = tsl[b];

  __shared__ bf16 Pl[4][2][16*PSTR];

  const size_t bh = (size_t)b*H_ + h;
  const bf16* qb = qp + bh*S_*DH_;
  const bf16* kb = kp + bh*S_*DH_;
  const bf16* vb = vt + bh*DH_*S_;

  const bf16x8 qf = *(const bf16x8*)(qb + (size_t)(q0 + l15)*DH_ + quad*8);

  float lacc = 0.f;
  f32x4 o0 = {0.f,0.f,0.f,0.f}, o1 = {0.f,0.f,0.f,0.f};

  const int qr = q0 + l15;
  const bool full = (len >= S_);
  const int dt = sid >> 2;

  auto make_p = [&](int t, const bf16x8* kfr) {
    bf16* pw = &Pl[wave][t & 1][0];
    f32x4 s[4];
    #pragma unroll
    for (int nt = 0; nt < 4; ++nt) {
      const f32x4 z = {0.f,0.f,0.f,0.f};
      s[nt] = __builtin_amdgcn_mfma_f32_16x16x32_bf16(kfr[nt], qf, z, 0, 0, 0);
    }
    const int k0 = t*64;
    #pragma unroll
    for (int nt = 0; nt < 4; ++nt) {
      float p0, p1, p2, p3;
      if (full && t < dt) {
        p0 = exp2f(s[nt][0]);
        p1 = exp2f(s[nt][1]);
        p2 = exp2f(s[nt][2]);
        p3 = exp2f(s[nt][3]);
      } else {
        const int kbase = k0 + nt*16 + quad*4;
        const bool okq = (qr < len);
        p0 = (okq && kbase+0 <= qr && kbase+0 < len) ? exp2f(s[nt][0]) : 0.f;
        p1 = (okq && kbase+1 <= qr && kbase+1 < len) ? exp2f(s[nt][1]) : 0.f;
        p2 = (okq && kbase+2 <= qr && kbase+2 < len) ? exp2f(s[nt][2]) : 0.f;
        p3 = (okq && kbase+3 <= qr && kbase+3 < len) ? exp2f(s[nt][3]) : 0.f;
      }
      lacc += (p0 + p1) + (p2 + p3);
      uint2 w;
      w.x = (unsigned)f2b(p0) | ((unsigned)f2b(p1) << 16);
      w.y = (unsigned)f2b(p2) | ((unsigned)f2b(p3) << 16);
      *(uint2*)((char*)pw + l15*(PSTR*2) + nt*32 + quad*8) = w;
    }
  };

  bf16x8 kf[4], vf[4];
  #pragma unroll
  for (int nt = 0; nt < 4; ++nt)
    kf[nt] = *(const bf16x8*)(kb + (size_t)(nt*16 + l15)*DH_ + quad*8);
  #pragma unroll
  for (int kc = 0; kc < 2; ++kc) {
    vf[kc*2]   = *(const bf16x8*)(vb + (size_t)l15*S_      + kc*32 + quad*8);
    vf[kc*2+1] = *(const bf16x8*)(vb + (size_t)(16+l15)*S_ + kc*32 + quad*8);
  }
  make_p(0, kf);
  if (dt > 0) {
    #pragma unroll
    for (int nt = 0; nt < 4; ++nt)
      kf[nt] = *(const bf16x8*)(kb + (size_t)(64 + nt*16 + l15)*DH_ + quad*8);
  }

  for (int ks = 0; ks <= dt; ++ks) {
    const bf16* rb = &Pl[wave][ks & 1][0];
    bf16x8 pf[2];
    pf[0] = *(const bf16x8*)(rb + l15*PSTR + quad*8);
    pf[1] = *(const bf16x8*)(rb + l15*PSTR + 32 + quad*8);

    if (ks < dt) {
      make_p(ks + 1, kf);
      if (ks + 1 < dt) {
        const int k2 = (ks + 2)*64;
        #pragma unroll
        for (int nt = 0; nt < 4; ++nt)
          kf[nt] = *(const bf16x8*)(kb + (size_t)(k2 + nt*16 + l15)*DH_ + quad*8);
      }
    }

    o0 = __builtin_amdgcn_mfma_f32_16x16x32_bf16(pf[0], vf[0], o0, 0, 0, 0);
    o1 = __builtin_amdgcn_mfma_f32_16x16x32_bf16(pf[0], vf[1], o1, 0, 0, 0);
    o0 = __builtin_amdgcn_mfma_f32_16x16x32_bf16(pf[1], vf[2], o0, 0, 0, 0);
    o1 = __builtin_amdgcn_mfma_f32_16x16x32_bf16(pf[1], vf[3], o1, 0, 0, 0);

    if (ks < dt) {
      const int k1 = (ks + 1)*64;
      #pragma unroll
      for (int kc = 0; kc < 2; ++kc) {
        vf[kc*2]   = *(const bf16x8*)(vb + (size_t)l15*S_      + k1 + kc*32 + quad*8);
        vf[kc*2+1] = *(const bf16x8*)(vb + (size_t)(16+l15)*S_ + k1 + kc*32 + quad*8);
      }
    }
  }

  float lt = lacc;
  lt += __shfl_xor(lt, 16);
  lt += __shfl_xor(lt, 32);

  bf16* ob = out + (size_t)b*S_*D_ + h*DH_;
  #pragma unroll
  for (int r = 0; r < 4; ++r) {
    const float lr = __shfl(lt, (lane & 48) | (quad*4 + r));
    const float inv = 1.f / fmaxf(lr, 1e-30f);
    const size_t rowoff = (size_t)(q0 + quad*4 + r)*D_;
    ob[rowoff + l15]      = (bf16)(o0[r]*inv);
    ob[rowoff + 16 + l15] = (bf16)(o1[r]*inv);
  }
}

// ---------------------------------------------------------------------------
extern "C" void kernel_launch(void* const* d_in, const int* in_sizes, int n_in,
                              void* d_out, int out_size, void* d_ws, size_t ws_size,
                              hipStream_t stream)
{
  const int*   ids = (const int*)d_in[0];
  const int*   tsl = (const int*)d_in[1];
  const float* emb = (const float*)d_in[2];
  const float* Wq  = (const float*)d_in[3];
  const float* bq  = (const float*)d_in[4];
  const float* Wk  = (const float*)d_in[5];
  const float* bk  = (const float*)d_in[6];
  const float* Wv  = (const float*)d_in[7];
  const float* bv  = (const float*)d_in[8];
  const float* Wo  = (const float*)d_in[9];
  const float* bo  = (const float*)d_in[10];
  const float* W1  = (const float*)d_in[11];
  const float* b1  = (const float*)d_in[12];
  const float* W2  = (const float*)d_in[13];
  const float* b2  = (const float*)d_in[14];
  const float* g1  = (const float*)d_in[15];
  const float* be1 = (const float*)d_in[16];
  const float* g2  = (const float*)d_in[17];
  const float* be2 = (const float*)d_in[18];
  const float* Wc  = (const float*)d_in[19];
  const float* bc  = (const float*)d_in[20];

  if (ws_size < (size_t)40*1024*1024) return;

  char* p = (char*)d_ws;
  auto carve = [&](size_t bytes) { void* r = (void*)p; p += (bytes + 255) & ~(size_t)255; return r; };
  bf16*  x     = (bf16*) carve((size_t)M_*D_*2);
  char*  big   = (char*) carve((size_t)M_*DFF_*2);
  char*  pkbuf = (char*) carve((size_t)12*1024*1024);
  bf16*  WqkvT = (bf16*) carve((size_t)L_*768*256*2);
  bf16*  WoT   = (bf16*) carve((size_t)L_*65536*2);
  bf16*  W1T   = (bf16*) carve((size_t)L_*262144*2);
  bf16*  W2T   = (bf16*) carve((size_t)L_*262144*2);
  bf16*  WcT   = (bf16*) carve((size_t)128*256*2);
  float* bqkv  = (float*)carve((size_t)L_*768*4);

  bf16*  aout = (bf16*)big;
  bf16*  ff1  = (bf16*)big;
  bf16*  qp   = (bf16*)pkbuf;
  bf16*  kp   = (bf16*)(pkbuf + (size_t)4*1024*1024);
  bf16*  vt   = (bf16*)(pkbuf + (size_t)8*1024*1024);

  prep_t<<<dim3(32,32,34), dim3(32,8), 0, stream>>>(Wq,Wk,Wv,Wo,W1,W2,Wc,bq,bk,bv,
                                                    ids, emb,
                                                    WqkvT,WoT,W1T,W2T,WcT,bqkv, x);

  for (int l = 0; l < L_; ++l) {
    gemm_qkv<<<dim3(64,12), 256, 0, stream>>>(
        x, WqkvT + (size_t)l*768*256, bqkv + l*768, qp, kp, vt);
    attn_kernel<<<dim3(16,8,8), 256, 0, stream>>>(qp, kp, vt, tsl, aout);
    gemm_ln<<<dim3(512), 256, 0, stream>>>(
        aout, WoT + (size_t)l*65536, bo + l*256, g1 + l*256, be1 + l*256, x, 256);
    gemm_bt<true,true><<<dim3(64,16), 256, 0, stream>>>(
        x, W1T + (size_t)l*262144, b1 + l*1024, ff1, M_, 1024, 256);
    gemm_ln<<<dim3(512), 256, 0, stream>>>(
        ff1, W2T + (size_t)l*262144, b2 + l*256, g2 + l*256, be2 + l*256, x, 1024);
  }

  gemm_bt64<false,false,true><<<dim3(128,2), 256, 0, stream>>>(
      x, WcT, bc, (float*)d_out, M_, V_, 256);
}